// Round 16
// baseline (750.689 us; speedup 1.0000x reference)
//
#include <hip/hip_runtime.h>
#include <hip/hip_bf16.h>

typedef __attribute__((ext_vector_type(8))) short short8;
typedef __attribute__((ext_vector_type(4))) float f32x4;

__device__ __forceinline__ unsigned short f2bf(float x) {
    unsigned int u = __builtin_bit_cast(unsigned int, x);
    unsigned int r = (u + 0x7FFFu + ((u >> 16) & 1u)) >> 16;
    return (unsigned short)r;
}

__device__ __forceinline__ void gload_lds16(const unsigned short* g, unsigned short* l) {
    __builtin_amdgcn_global_load_lds(
        (const __attribute__((address_space(1))) unsigned int*)g,
        (__attribute__((address_space(3))) unsigned int*)l, 16, 0, 0);
}

// ---------------- 128x256 / BK=32 / 4-wave GEMM (QKV) ----------------
// __launch_bounds__(256, 1): explicit min-waves=1 -> max VGPR budget. All prior
// fat-acc kernels spilled because the allocator's DEFAULT occupancy target caps
// ~96-102 VGPR (rounds 9-11,14). This is the decisive allocator-budget probe.
// Ring-3 LDS (72KB), depth-2 prefetch, counted vmcnt 12/6/0 (round-11 schedule,
// correctness-proven). Per wave: 128x64 out, 32 MFMA/step.
// mode 2: qkv scatter -> q/k bf16 [z][196][128], v_t bf16 [z][128][224]
__global__ __launch_bounds__(256, 1) void gemm_wide(
    const unsigned short* __restrict__ A, int lda,
    const unsigned short* __restrict__ B, int ldb,
    const float* __restrict__ bias,
    int K,
    unsigned short* q_out, unsigned short* k_out, unsigned short* v_out,
    float qscale)
{
    // general bijective XCD swizzle (m204, any grid size)
    int bx = blockIdx.x, by = blockIdx.y;
    {
        const int gx = gridDim.x;
        const int total = gx * gridDim.y;
        const int orig = by * gx + bx;
        const int q = total >> 3, r = total & 7;
        const int xcd = orig & 7, idx = orig >> 3;
        const int nf = (xcd < r ? xcd * (q + 1) : r * (q + 1) + (xcd - r) * q) + idx;
        bx = nf % gx;
        by = nf / gx;
    }
    const int bm = by * 128;
    const int bn = bx * 256;

    __shared__ unsigned short As[3][128][32];
    __shared__ unsigned short Bs[3][256][32];

    const int tid  = threadIdx.x;
    const int lane = tid & 63;
    const int wid  = tid >> 6;      // 0..3 = N quarter
    const int slot = lane >> 4;
    const int lcol = lane & 15;

    const int srow = tid >> 2;      // 0..63
    const int sgrn = tid & 3;
    const int scol_dst = sgrn * 8;
    const int scol_src = (sgrn ^ ((srow >> 1) & 3)) * 8;
    const int rslot = (slot ^ ((lcol >> 1) & 3)) * 8;

    const unsigned short* pa0 = A + (long long)(bm + srow) * lda + scol_src;
    const unsigned short* pa1 = A + (long long)(bm + 64 + srow) * lda + scol_src;
    const unsigned short* pb0 = B + (long long)(bn + srow) * ldb + scol_src;
    const unsigned short* pb1 = B + (long long)(bn + 64 + srow) * ldb + scol_src;
    const unsigned short* pb2 = B + (long long)(bn + 128 + srow) * ldb + scol_src;
    const unsigned short* pb3 = B + (long long)(bn + 192 + srow) * ldb + scol_src;

    f32x4 acc[8][4];
    #pragma unroll
    for (int i = 0; i < 8; ++i)
        #pragma unroll
        for (int j = 0; j < 4; ++j)
            acc[i][j] = (f32x4){0.f, 0.f, 0.f, 0.f};

    const int nt = K >> 5;   // 16 for K=512

    gload_lds16(pa0, &As[0][srow][scol_dst]);
    gload_lds16(pa1, &As[0][64 + srow][scol_dst]);
    gload_lds16(pb0, &Bs[0][srow][scol_dst]);
    gload_lds16(pb1, &Bs[0][64 + srow][scol_dst]);
    gload_lds16(pb2, &Bs[0][128 + srow][scol_dst]);
    gload_lds16(pb3, &Bs[0][192 + srow][scol_dst]);
    gload_lds16(pa0 + 32, &As[1][srow][scol_dst]);
    gload_lds16(pa1 + 32, &As[1][64 + srow][scol_dst]);
    gload_lds16(pb0 + 32, &Bs[1][srow][scol_dst]);
    gload_lds16(pb1 + 32, &Bs[1][64 + srow][scol_dst]);
    gload_lds16(pb2 + 32, &Bs[1][128 + srow][scol_dst]);
    gload_lds16(pb3 + 32, &Bs[1][192 + srow][scol_dst]);

    int cur = 0;
    for (int t = 0; t < nt; ++t) {
        const int nxt2 = t + 2;
        if (nxt2 < nt) {
            const int nb = nxt2 % 3;
            const long long koff = (long long)nxt2 << 5;
            gload_lds16(pa0 + koff, &As[nb][srow][scol_dst]);
            gload_lds16(pa1 + koff, &As[nb][64 + srow][scol_dst]);
            gload_lds16(pb0 + koff, &Bs[nb][srow][scol_dst]);
            gload_lds16(pb1 + koff, &Bs[nb][64 + srow][scol_dst]);
            gload_lds16(pb2 + koff, &Bs[nb][128 + srow][scol_dst]);
            gload_lds16(pb3 + koff, &Bs[nb][192 + srow][scol_dst]);
        }
        if (nxt2 < nt)          asm volatile("s_waitcnt vmcnt(12)" ::: "memory");
        else if (t + 1 < nt)    asm volatile("s_waitcnt vmcnt(6)" ::: "memory");
        else                    asm volatile("s_waitcnt vmcnt(0)" ::: "memory");
        __builtin_amdgcn_s_barrier();
        __builtin_amdgcn_sched_barrier(0);

        short8 afr[8], bfr[4];
        #pragma unroll
        for (int mi = 0; mi < 8; ++mi)
            afr[mi] = *(const short8*)&As[cur][mi * 16 + lcol][rslot];
        #pragma unroll
        for (int ni = 0; ni < 4; ++ni)
            bfr[ni] = *(const short8*)&Bs[cur][wid * 64 + ni * 16 + lcol][rslot];
        #pragma unroll
        for (int mi = 0; mi < 8; ++mi)
            #pragma unroll
            for (int ni = 0; ni < 4; ++ni)
                acc[mi][ni] = __builtin_amdgcn_mfma_f32_16x16x32_bf16(
                    afr[mi], bfr[ni], acc[mi][ni], 0, 0, 0);

        __builtin_amdgcn_s_barrier();
        cur = (cur == 2) ? 0 : cur + 1;
    }

    // ---- epilogue: qkv scatter only ----
    #pragma unroll
    for (int mi = 0; mi < 8; ++mi) {
        int rbase = bm + mi * 16 + slot * 4;
        #pragma unroll
        for (int ni = 0; ni < 4; ++ni) {
            int gc = bn + wid * 64 + ni * 16 + lcol;
            float bv = bias[gc];
            f32x4 a = acc[mi][ni];
            int which = gc >> 9;
            int hh = (gc >> 7) & 3;
            int d  = gc & 127;
            #pragma unroll
            for (int rr = 0; rr < 4; ++rr) {
                int gr = rbase + rr;
                float v = a[rr] + bv;
                int b_ = gr / 196, l_ = gr % 196;
                int zz = b_ * 4 + hh;
                if (which == 0)
                    q_out[((long long)zz * 196 + l_) * 128 + d] = f2bf(v * qscale);
                else if (which == 1)
                    k_out[((long long)zz * 196 + l_) * 128 + d] = f2bf(v);
                else
                    v_out[((long long)zz * 128 + d) * 224 + l_] = f2bf(v);
            }
        }
    }
}

// ---------------- 128x128 / BK=64 GEMM (attnproj, MLP1, MLP2) ----------------
__global__ __launch_bounds__(256) void gemm64(
    const unsigned short* __restrict__ A, int lda,
    const unsigned short* __restrict__ B, int ldb,
    void* __restrict__ Cv, int ldc,
    const float* __restrict__ bias,
    const float* __restrict__ res, int ldres,
    int K, int relu, int mode,
    unsigned short* q_out, unsigned short* k_out, unsigned short* v_out,
    float qscale)
{
    int bx = blockIdx.x, by = blockIdx.y;
    {
        const int gx = gridDim.x;
        const int total = gx * gridDim.y;
        if ((total & 7) == 0) {
            const int orig = by * gx + bx;
            const int per = total >> 3;
            const int nf = (orig & 7) * per + (orig >> 3);
            bx = nf % gx;
            by = nf / gx;
        }
    }
    const int bm = by * 128;
    const int bn = bx * 128;

    __shared__ unsigned short As[2][128][64];
    __shared__ unsigned short Bs[2][128][64];

    const int tid  = threadIdx.x;
    const int lane = tid & 63;
    const int wid  = tid >> 6;
    const int wm   = wid >> 1;
    const int wn   = wid & 1;
    const int slot = lane >> 4;
    const int lcol = lane & 15;

    const int trow = tid >> 3;               // 0..31
    const int tgrn = tid & 7;
    const int scol_dst = tgrn * 8;
    const int scol_src = (tgrn ^ (trow & 7)) * 8;

    const unsigned short* pa[4];
    const unsigned short* pb[4];
    #pragma unroll
    for (int p = 0; p < 4; ++p) {
        pa[p] = A + (long long)(bm + p * 32 + trow) * lda + scol_src;
        pb[p] = B + (long long)(bn + p * 32 + trow) * ldb + scol_src;
    }

    f32x4 acc[4][4];
    #pragma unroll
    for (int i = 0; i < 4; ++i)
        #pragma unroll
        for (int j = 0; j < 4; ++j)
            acc[i][j] = (f32x4){0.f, 0.f, 0.f, 0.f};

    const int nt = K >> 6;

    #pragma unroll
    for (int p = 0; p < 4; ++p) {
        gload_lds16(pa[p], &As[0][p * 32 + trow][scol_dst]);
        gload_lds16(pb[p], &Bs[0][p * 32 + trow][scol_dst]);
    }
    __syncthreads();

    for (int t = 0; t < nt; ++t) {
        const int cur = t & 1;
        if (t + 1 < nt) {
            const int nb = (t + 1) & 1;
            const long long koff = (long long)(t + 1) << 6;
            #pragma unroll
            for (int p = 0; p < 4; ++p) {
                gload_lds16(pa[p] + koff, &As[nb][p * 32 + trow][scol_dst]);
                gload_lds16(pb[p] + koff, &Bs[nb][p * 32 + trow][scol_dst]);
            }
        }

        short8 afr[4][2], bfr[4][2];
        #pragma unroll
        for (int mi = 0; mi < 4; ++mi) {
            const int row = wm * 64 + mi * 16 + lcol;
            #pragma unroll
            for (int ks = 0; ks < 2; ++ks) {
                const int g = ((ks * 4 + slot) ^ (lcol & 7)) * 8;
                afr[mi][ks] = *(const short8*)&As[cur][row][g];
            }
        }
        #pragma unroll
        for (int ni = 0; ni < 4; ++ni) {
            const int row = wn * 64 + ni * 16 + lcol;
            #pragma unroll
            for (int ks = 0; ks < 2; ++ks) {
                const int g = ((ks * 4 + slot) ^ (lcol & 7)) * 8;
                bfr[ni][ks] = *(const short8*)&Bs[cur][row][g];
            }
        }
        #pragma unroll
        for (int mi = 0; mi < 4; ++mi)
            #pragma unroll
            for (int ni = 0; ni < 4; ++ni)
                #pragma unroll
                for (int ks = 0; ks < 2; ++ks)
                    acc[mi][ni] = __builtin_amdgcn_mfma_f32_16x16x32_bf16(
                        afr[mi][ks], bfr[ni][ks], acc[mi][ni], 0, 0, 0);

        __syncthreads();
    }

    float* Cf = (float*)Cv;
    unsigned short* Cb = (unsigned short*)Cv;

    #pragma unroll
    for (int mi = 0; mi < 4; ++mi) {
        int rbase = bm + wm * 64 + mi * 16 + slot * 4;
        #pragma unroll
        for (int ni = 0; ni < 4; ++ni) {
            int gc = bn + wn * 64 + ni * 16 + lcol;
            float bv = bias ? bias[gc] : 0.f;
            f32x4 a = acc[mi][ni];
            #pragma unroll
            for (int rr = 0; rr < 4; ++rr) {
                int gr = rbase + rr;
                float v = a[rr] + bv;
                if (mode == 0) {
                    if (res) v += res[(long long)gr * ldres + gc];
                    if (relu) v = fmaxf(v, 0.f);
                    Cf[(long long)gr * ldc + gc] = v;
                } else { // mode 4
                    if (relu) v = fmaxf(v, 0.f);
                    Cb[(long long)gr * ldc + gc] = f2bf(v);
                }
            }
        }
    }
}

// ---------------- 128x128 BK=32 ring-3 GEMM (proj-stage) ----------------
// mode 1: proj row remap into X: orow=(r/49)*196+rowoff+r%49 (fp32)
__global__ __launch_bounds__(256) void gemm_bf16(
    const unsigned short* __restrict__ A, long long sA, int lda,
    const unsigned short* __restrict__ B, long long sB, int ldb,
    void* __restrict__ Cv, long long sC, int ldc,
    const float* __restrict__ bias,
    const float* __restrict__ res, int ldres,
    int M, int N, int K,
    int relu, int mode, int rowoff,
    unsigned short* q_out, unsigned short* k_out, unsigned short* v_out,
    float qscale)
{
    const int z = blockIdx.z;
    A += (long long)z * sA;
    B += (long long)z * sB;

    const int bm = blockIdx.y * 128;
    const int bn = blockIdx.x * 128;

    __shared__ unsigned short As[3][128][32];
    __shared__ unsigned short Bs[3][128][32];

    const int tid  = threadIdx.x;
    const int lane = tid & 63;
    const int wid  = tid >> 6;
    const int wm   = wid >> 1;
    const int wn   = wid & 1;
    const int slot = lane >> 4;
    const int lcol = lane & 15;

    const int srow = tid >> 2;
    const int sgrn = tid & 3;
    const int scol_dst = sgrn * 8;
    const int scol_src = (sgrn ^ ((srow >> 1) & 3)) * 8;
    const int rslot = (slot ^ ((lcol >> 1) & 3)) * 8;

    int ga0 = bm + srow;       if (ga0 > M - 1) ga0 = M - 1;
    int ga1 = bm + 64 + srow;  if (ga1 > M - 1) ga1 = M - 1;
    int gb0 = bn + srow;       if (gb0 > N - 1) gb0 = N - 1;
    int gb1 = bn + 64 + srow;  if (gb1 > N - 1) gb1 = N - 1;
    const unsigned short* pa0 = A + (long long)ga0 * lda + scol_src;
    const unsigned short* pa1 = A + (long long)ga1 * lda + scol_src;
    const unsigned short* pb0 = B + (long long)gb0 * ldb + scol_src;
    const unsigned short* pb1 = B + (long long)gb1 * ldb + scol_src;

    f32x4 acc[4][4];
    #pragma unroll
    for (int i = 0; i < 4; ++i)
        #pragma unroll
        for (int j = 0; j < 4; ++j)
            acc[i][j] = (f32x4){0.f, 0.f, 0.f, 0.f};

    const int nt = K >> 5;

    gload_lds16(pa0, &As[0][srow][scol_dst]);
    gload_lds16(pa1, &As[0][64 + srow][scol_dst]);
    gload_lds16(pb0, &Bs[0][srow][scol_dst]);
    gload_lds16(pb1, &Bs[0][64 + srow][scol_dst]);
    if (nt > 1) {
        gload_lds16(pa0 + 32, &As[1][srow][scol_dst]);
        gload_lds16(pa1 + 32, &As[1][64 + srow][scol_dst]);
        gload_lds16(pb0 + 32, &Bs[1][srow][scol_dst]);
        gload_lds16(pb1 + 32, &Bs[1][64 + srow][scol_dst]);
    }

    int cur = 0;
    for (int t = 0; t < nt; ++t) {
        const int nxt2 = t + 2;
        if (nxt2 < nt) {
            const int nb = nxt2 % 3;
            const long long koff = (long long)nxt2 << 5;
            gload_lds16(pa0 + koff, &As[nb][srow][scol_dst]);
            gload_lds16(pa1 + koff, &As[nb][64 + srow][scol_dst]);
            gload_lds16(pb0 + koff, &Bs[nb][srow][scol_dst]);
            gload_lds16(pb1 + koff, &Bs[nb][64 + srow][scol_dst]);
        }
        if (nxt2 < nt)          asm volatile("s_waitcnt vmcnt(8)" ::: "memory");
        else if (t + 1 < nt)    asm volatile("s_waitcnt vmcnt(4)" ::: "memory");
        else                    asm volatile("s_waitcnt vmcnt(0)" ::: "memory");
        __builtin_amdgcn_s_barrier();
        __builtin_amdgcn_sched_barrier(0);

        short8 afr[4], bfr[4];
        #pragma unroll
        for (int mi = 0; mi < 4; ++mi)
            afr[mi] = *(const short8*)&As[cur][wm * 64 + mi * 16 + lcol][rslot];
        #pragma unroll
        for (int ni = 0; ni < 4; ++ni)
            bfr[ni] = *(const short8*)&Bs[cur][wn * 64 + ni * 16 + lcol][rslot];
        #pragma unroll
        for (int mi = 0; mi < 4; ++mi)
            #pragma unroll
            for (int ni = 0; ni < 4; ++ni)
                acc[mi][ni] = __builtin_amdgcn_mfma_f32_16x16x32_bf16(
                    afr[mi], bfr[ni], acc[mi][ni], 0, 0, 0);

        __builtin_amdgcn_s_barrier();
        cur = (cur == 2) ? 0 : cur + 1;
    }

    float* Cf = (float*)Cv + (mode == 0 ? (long long)z * sC : 0);

    #pragma unroll
    for (int mi = 0; mi < 4; ++mi) {
        int rbase = bm + wm * 64 + mi * 16 + slot * 4;
        #pragma unroll
        for (int ni = 0; ni < 4; ++ni) {
            int gc = bn + wn * 64 + ni * 16 + lcol;
            if (gc >= N) continue;
            float bv = bias ? bias[gc] : 0.f;
            f32x4 a = acc[mi][ni];
            #pragma unroll
            for (int rr = 0; rr < 4; ++rr) {
                int gr = rbase + rr;
                if (gr >= M) continue;
                float v = a[rr] + bv;
                if (mode == 0) {
                    if (res) v += res[(long long)gr * ldres + gc];
                    if (relu) v = fmaxf(v, 0.f);
                    Cf[(long long)gr * ldc + gc] = v;
                } else { // mode 1
                    int orow = (gr / 49) * 196 + rowoff + (gr % 49);
                    Cf[(long long)orow * ldc + gc] = v;
                }
            }
        }
    }
}

// ---------------- fused flash attention (round-12, unchanged) ----------------
__global__ __launch_bounds__(256) void flash_k(
    const unsigned short* __restrict__ q_bf,
    const unsigned short* __restrict__ k_bf,
    const unsigned short* __restrict__ v_t,
    unsigned short* __restrict__ O,
    const float* __restrict__ bt)
{
    const int z = blockIdx.x;
    const int h = z & 3, bb = z >> 2;
    const int tid = threadIdx.x;
    const int w = tid >> 6;
    const int lane = tid & 63;
    const int slot = lane >> 4;
    const int lcol = lane & 15;

    __shared__ unsigned short Ps[4][16][68];

    const unsigned short* Qz = q_bf + (long long)z * 196 * 128;
    const unsigned short* Kz = k_bf + (long long)z * 196 * 128;
    const unsigned short* Vz = v_t  + (long long)z * 128 * 224;

    short8 qf[4][4];
    #pragma unroll
    for (int i = 0; i < 4; ++i) {
        const int row = (w + 4 * i) * 16 + lcol;
        #pragma unroll
        for (int ks = 0; ks < 4; ++ks)
            qf[i][ks] = *(const short8*)(Qz + (long long)row * 128 + ks * 32 + slot * 8);
    }

    f32x4 o[4][8];
    #pragma unroll
    for (int i = 0; i < 4; ++i)
        #pragma unroll
        for (int nd = 0; nd < 8; ++nd)
            o[i][nd] = (f32x4){0.f, 0.f, 0.f, 0.f};

    float m_r[4][4], l_r[4][4];
    #pragma unroll
    for (int i = 0; i < 4; ++i)
        #pragma unroll
        for (int r = 0; r < 4; ++r) { m_r[i][r] = -3e38f; l_r[i][r] = 0.f; }

    int qi1[4][4], qj1[4][4];
    #pragma unroll
    for (int i = 0; i < 4; ++i)
        #pragma unroll
        for (int r = 0; r < 4; ++r) {
            int q = (w + 4 * i) * 16 + slot * 4 + r;
            int qq = q < 195 ? q : 195;
            qi1[i][r] = qq / 14;
            qj1[i][r] = qq % 14;
        }

    #pragma unroll
    for (int kt = 0; kt < 4; ++kt) {
        const int nkj  = (kt == 3) ? 2 : 4;
        const int nksl = (kt == 3) ? 1 : 2;

        short8 kf[4][4];
        #pragma unroll
        for (int kj = 0; kj < 4; ++kj) {
            if (kj >= nkj) continue;
            const int krow = kt * 64 + kj * 16 + lcol;
            #pragma unroll
            for (int ks = 0; ks < 4; ++ks)
                kf[kj][ks] = *(const short8*)(Kz + (long long)krow * 128 + ks * 32 + slot * 8);
        }

        f32x4 s[4][4];
        __builtin_amdgcn_s_setprio(1);
        #pragma unroll
        for (int i = 0; i < 4; ++i)
            #pragma unroll
            for (int kj = 0; kj < 4; ++kj) {
                if (kj >= nkj) continue;
                f32x4 a = (f32x4){0.f, 0.f, 0.f, 0.f};
                #pragma unroll
                for (int ks = 0; ks < 4; ++ks)
                    a = __builtin_amdgcn_mfma_f32_16x16x32_bf16(qf[i][ks], kf[kj][ks], a, 0, 0, 0);
                s[i][kj] = a;
            }
        __builtin_amdgcn_s_setprio(0);

        short8 vf[8][2];
        #pragma unroll
        for (int nd = 0; nd < 8; ++nd)
            #pragma unroll
            for (int ksl = 0; ksl < 2; ++ksl) {
                if (ksl >= nksl) continue;
                vf[nd][ksl] = *(const short8*)(Vz + (long long)(nd * 16 + lcol) * 224
                                               + kt * 64 + ksl * 32 + slot * 8);
            }

        #pragma unroll
        for (int i = 0; i < 4; ++i) {
            #pragma unroll
            for (int kj = 0; kj < 4; ++kj) {
                if (kj >= nkj) continue;
                const int key = kt * 64 + kj * 16 + lcol;
                const int kk = key < 195 ? key : 195;
                const int i2 = kk / 14, j2 = kk % 14;
                #pragma unroll
                for (int r = 0; r < 4; ++r) {
                    const int idx = (qi1[i][r] - i2 + 13) * 27 + (qj1[i][r] - j2 + 13);
                    float sv = s[i][kj][r] + bt[idx * 4 + h];
                    if (key >= 196) sv = -3e38f;
                    s[i][kj][r] = sv;
                }
            }
            f32x4 pm = s[i][0];
            #pragma unroll
            for (int kj = 1; kj < 4; ++kj) {
                if (kj >= nkj) continue;
                #pragma unroll
                for (int r = 0; r < 4; ++r) pm[r] = fmaxf(pm[r], s[i][kj][r]);
            }
            #pragma unroll
            for (int r = 0; r < 4; ++r) {
                #pragma unroll
                for (int off = 1; off < 16; off <<= 1)
                    pm[r] = fmaxf(pm[r], __shfl_xor(pm[r], off));
            }
            float sf[4];
            #pragma unroll
            for (int r = 0; r < 4; ++r) {
                float mn = fmaxf(m_r[i][r], pm[r]);
                sf[r] = __expf(m_r[i][r] - mn);
                m_r[i][r] = mn;
            }
            f32x4 ladd = (f32x4){0.f, 0.f, 0.f, 0.f};
            #pragma unroll
            for (int kj = 0; kj < 4; ++kj) {
                if (kj >= nkj) continue;
                #pragma unroll
                for (int r = 0; r < 4; ++r) {
                    float p = __expf(s[i][kj][r] - m_r[i][r]);
                    s[i][kj][r] = p;
                    ladd[r] += p;
                }
            }
            #pragma unroll
            for (int r = 0; r < 4; ++r) {
                #pragma unroll
                for (int off = 1; off < 16; off <<= 1)
                    ladd[r] += __shfl_xor(ladd[r], off);
                l_r[i][r] = l_r[i][r] * sf[r] + ladd[r];
            }
            #pragma unroll
            for (int nd = 0; nd < 8; ++nd)
                #pragma unroll
                for (int r = 0; r < 4; ++r) o[i][nd][r] *= sf[r];
            #pragma unroll
            for (int kj = 0; kj < 4; ++kj) {
                if (kj >= nkj) continue;
                #pragma unroll
                for (int r = 0; r < 4; ++r)
                    Ps[w][slot * 4 + r][kj * 16 + lcol] = f2bf(s[i][kj][r]);
            }
            __builtin_amdgcn_s_setprio(1);
            #pragma unroll
            for (int ksl = 0; ksl < 2; ++ksl) {
                if (ksl >= nksl) continue;
                short8 pa = *(const short8*)&Ps[w][lcol][ksl * 32 + slot * 8];
                #pragma unroll
                for (int nd = 0; nd < 8; ++nd)
                    o[i][nd] = __builtin_amdgcn_mfma_f32_16x16x32_bf16(pa, vf[nd][ksl], o[i][nd], 0, 0, 0);
            }
            __builtin_amdgcn_s_setprio(0);
        }
    }

    #pragma unroll
    for (int i = 0; i < 4; ++i) {
        #pragma unroll
        for (int r = 0; r < 4; ++r) {
            const int q = (w + 4 * i) * 16 + slot * 4 + r;
            if (q >= 196) continue;
            const float rn = 1.f / l_r[i][r];
            unsigned short* op = O + ((long long)(bb * 196 + q)) * 512 + h * 128 + lcol;
            #pragma unroll
            for (int nd = 0; nd < 8; ++nd)
                op[nd * 16] = f2bf(o[i][nd][r] * rn);
        }
    }
}

// transpose+convert W[K][N] f32 -> Wt[N][K] bf16, layers via blockIdx.z
__global__ __launch_bounds__(256) void wconv_t(const float* __restrict__ W,
                                               unsigned short* __restrict__ Wt,
                                               int K, int N)
{
    W  += (long long)blockIdx.z * K * N;
    Wt += (long long)blockIdx.z * K * N;
    __shared__ float t[32][33];
    int tx = threadIdx.x & 31, ty = threadIdx.x >> 5;
    int n0 = blockIdx.x * 32, k0 = blockIdx.y * 32;
    #pragma unroll
    for (int j = 0; j < 4; ++j)
        t[ty + j * 8][tx] = W[(long long)(k0 + ty + j * 8) * N + n0 + tx];
    __syncthreads();
    #pragma unroll
    for (int j = 0; j < 4; ++j)
        Wt[(long long)(n0 + ty + j * 8) * K + k0 + tx] = f2bf(t[tx][ty + j * 8]);
}

__global__ __launch_bounds__(256) void wcv_k(const float* __restrict__ in,
                                             unsigned short* __restrict__ out, int n)
{
    int i = blockIdx.x * 256 + threadIdx.x;
    if (i < n) out[i] = f2bf(in[i]);
}

// adaptive avg-pool to 7x7 -> bf16 channels-last P[(b*49+t)*ch + c]
template<int F>
__global__ __launch_bounds__(256) void pool_k(const float* __restrict__ feat,
                                              unsigned short* __restrict__ P, int ch)
{
    const int S = 7 * F;
    int wv = blockIdx.x * 4 + (threadIdx.x >> 6);
    int lane = threadIdx.x & 63;
    int b = wv / ch, c = wv % ch;
    if (lane >= 49) return;
    int oh = lane / 7, ow = lane % 7;
    const float* src = feat + ((long long)b * ch + c) * (S * S) + (oh * F) * S + ow * F;
    float acc = 0.f;
    #pragma unroll
    for (int hh = 0; hh < F; ++hh) {
        const float* row = src + hh * S;
        if constexpr (F == 8) {
            float4 a = *(const float4*)row;
            float4 d = *(const float4*)(row + 4);
            acc += a.x + a.y + a.z + a.w + d.x + d.y + d.z + d.w;
        } else if constexpr (F == 4) {
            float4 a = *(const float4*)row;
            acc += a.x + a.y + a.z + a.w;
        } else if constexpr (F == 2) {
            float2 a = *(const float2*)row;
            acc += a.x + a.y;
        } else {
            acc += row[0];
        }
    }
    P[((long long)(b * 49 + lane)) * ch + c] = f2bf(acc * (1.f / (F * F)));
}

// LayerNorm over C=512 -> bf16 out; one wave per row, 4 rows/block
__global__ __launch_bounds__(256) void ln_k(const float* __restrict__ x,
                                            unsigned short* __restrict__ y,
                                            const float* __restrict__ g,
                                            const float* __restrict__ b)
{
    long long row = blockIdx.x * 4 + (threadIdx.x >> 6);
    const float* xr = x + row * 512;
    unsigned short* yr = y + row * 512;
    int lane = threadIdx.x & 63;
    float v[8];
    float s = 0.f, ss = 0.f;
    #pragma unroll
    for (int p = 0; p < 8; ++p) {
        v[p] = xr[lane + p * 64];
        s += v[p]; ss += v[p] * v[p];
    }
    #pragma unroll
    for (int off = 32; off >= 1; off >>= 1) {
        s  += __shfl_xor(s, off);
        ss += __shfl_xor(ss, off);
    }
    float mean = s * (1.f / 512.f);
    float var  = ss * (1.f / 512.f) - mean * mean;
    float rstd = rsqrtf(var + 1e-5f);
    #pragma unroll
    for (int p = 0; p < 8; ++p) {
        int c = lane + p * 64;
        yr[c] = f2bf((v[p] - mean) * rstd * g[c] + b[c]);
    }
}

__global__ __launch_bounds__(512) void mean_k(const float* __restrict__ X,
                                              float* __restrict__ out)
{
    int b = blockIdx.x, c = threadIdx.x;
    const float* xp = X + (long long)b * 196 * 512 + c;
    float s = 0.f;
    for (int t = 0; t < 196; ++t) s += xp[t * 512];
    out[b * 512 + c] = s * (1.f / 196.f);
}

extern "C" void kernel_launch(void* const* d_in, const int* in_sizes, int n_in,
                              void* d_out, int out_size, void* d_ws, size_t ws_size,
                              hipStream_t stream)
{
    const float* feat[4]   = {(const float*)d_in[0], (const float*)d_in[1],
                              (const float*)d_in[2], (const float*)d_in[3]};
    const float* proj_w[4] = {(const float*)d_in[4], (const float*)d_in[6],
                              (const float*)d_in[8], (const float*)d_in[10]};
    const float* proj_b[4] = {(const float*)d_in[5], (const float*)d_in[7],
                              (const float*)d_in[9], (const float*)d_in[11]};
    const float* ln1_g = (const float*)d_in[12];
    const float* ln1_b = (const float*)d_in[13];
    const float* qkv_w = (const float*)d_in[14];
    const float* qkv_b = (const float*)d_in[15];
    const float* bias_table = (const float*)d_in[16];
    const float* attn_pw = (const float*)d_in[17];
    const float* attn_pb = (const float*)d_in[18];
    const float* ln2_g = (const float*)d_in[19];
    const float* ln2_b = (const float*)d_in[20];
    const float* mlp_w1 = (const float*)d_in[21];
    const float* mlp_b1 = (const float*)d_in[22];
    const float* mlp_w2 = (const float*)d_in[23];
    const float* mlp_b2 = (const float*)d_in[24];

    const long long NXT = 64LL * 196 * 512;          // 6,422,528

    float* X  = (float*)d_ws;                        // [12544][512] f32
    float* S  = X + NXT;                             // scratch region
    unsigned short* O_bf = (unsigned short*)S;       // attention out [12544][512] bf16

    unsigned short* ub    = (unsigned short*)(S + 256LL * 196 * 196);
    unsigned short* XN_bf = ub;                          // [12544][512]
    unsigned short* q_bf  = XN_bf + NXT;                 // [256][196][128]
    unsigned short* k_bf  = q_bf + NXT;                  // [256][196][128]
    unsigned short* v_t   = k_bf + NXT;                  // [256][128][224]
    unsigned short* H     = q_bf;                        // MLP hidden aliases q..v_t
    unsigned short* wts   = v_t + 256LL * 128 * 224 + 256LL * 196 * 224;

    unsigned short* qkvw_t = wts;                        // 2 x [1536][512]
    unsigned short* pw_t   = qkvw_t + 2LL * 1536 * 512;  // 2 x [512][512]
    unsigned short* w1_t   = pw_t   + 2LL * 512 * 512;   // 2 x [2048][512]
    unsigned short* w2_t   = w1_t   + 2LL * 2048 * 512;  // 2 x [512][2048]
    unsigned short* pjw    = w2_t   + 2LL * 512 * 2048;
    unsigned short* P_bf   = pjw + 512LL * (96 + 192 + 384 + 768); // [3136][ch]
    unsigned short* pjw_i[4];
    const int chans[4] = {96, 192, 384, 768};
    {
        unsigned short* p = pjw;
        for (int i = 0; i < 4; ++i) { pjw_i[i] = p; p += 512LL * chans[i]; }
    }

    // ---- weight conversion ----
    wconv_t<<<dim3(1536/32, 512/32, 2), 256, 0, stream>>>(qkv_w, qkvw_t, 512, 1536);
    wconv_t<<<dim3(512/32, 512/32, 2), 256, 0, stream>>>(attn_pw, pw_t, 512, 512);
    wconv_t<<<dim3(2048/32, 512/32, 2), 256, 0, stream>>>(mlp_w1, w1_t, 512, 2048);
    wconv_t<<<dim3(512/32, 2048/32, 2), 256, 0, stream>>>(mlp_w2, w2_t, 2048, 512);
    for (int i = 0; i < 4; ++i) {
        int n = 512 * chans[i];
        wcv_k<<<(n + 255) / 256, 256, 0, stream>>>(proj_w[i], pjw_i[i], n);
    }

    // ---- pool + proj ----
    pool_k<8><<<64 * 96  / 4, 256, 0, stream>>>(feat[0], P_bf, 96);
    gemm_bf16<<<dim3(4, 25, 1), 256, 0, stream>>>(
        P_bf, 0, 96, pjw_i[0], 0, 96, X, 0, 512, proj_b[0], nullptr, 0,
        3136, 512, 96, 0, 1, 0, nullptr, nullptr, nullptr, 0.f);
    pool_k<4><<<64 * 192 / 4, 256, 0, stream>>>(feat[1], P_bf, 192);
    gemm_bf16<<<dim3(4, 25, 1), 256, 0, stream>>>(
        P_bf, 0, 192, pjw_i[1], 0, 192, X, 0, 512, proj_b[1], nullptr, 0,
        3136, 512, 192, 0, 1, 49, nullptr, nullptr, nullptr, 0.f);
    pool_k<2><<<64 * 384 / 4, 256, 0, stream>>>(feat[2], P_bf, 384);
    gemm_bf16<<<dim3(4, 25, 1), 256, 0, stream>>>(
        P_bf, 0, 384, pjw_i[2], 0, 384, X, 0, 512, proj_b[2], nullptr, 0,
        3136, 512, 384, 0, 1, 98, nullptr, nullptr, nullptr, 0.f);
    pool_k<1><<<64 * 768 / 4, 256, 0, stream>>>(feat[3], P_bf, 768);
    gemm_bf16<<<dim3(4, 25, 1), 256, 0, stream>>>(
        P_bf, 0, 768, pjw_i[3], 0, 768, X, 0, 512, proj_b[3], nullptr, 0,
        3136, 512, 768, 0, 1, 147, nullptr, nullptr, nullptr, 0.f);

    // ---- transformer layers ----
    for (int l = 0; l < 2; ++l) {
        ln_k<<<3136, 256, 0, stream>>>(X, XN_bf, ln1_g + l * 512, ln1_b + l * 512);

        // QKV: 128x256 tile, 32 MFMA/step (allocator-budget probe: (256,1))
        gemm_wide<<<dim3(6, 98), 256, 0, stream>>>(
            XN_bf, 512,
            qkvw_t + (long long)l * 1536 * 512, 512,
            qkv_b + l * 1536,
            512,
            q_bf, k_bf, v_t, 0.08838834764831845f);

        // fused attention
        flash_k<<<256, 256, 0, stream>>>(q_bf, k_bf, v_t, O_bf,
                                         bias_table + (long long)l * 729 * 4);

        gemm64<<<dim3(4, 98), 256, 0, stream>>>(
            O_bf, 512,
            pw_t + (long long)l * 512 * 512, 512,
            X, 512,
            attn_pb + l * 512, X, 512,
            512, 0, 0,
            nullptr, nullptr, nullptr, 0.f);

        ln_k<<<3136, 256, 0, stream>>>(X, XN_bf, ln2_g + l * 512, ln2_b + l * 512);

        gemm64<<<dim3(16, 98), 256, 0, stream>>>(
            XN_bf, 512,
            w1_t + (long long)l * 2048 * 512, 512,
            H, 2048,
            mlp_b1 + l * 2048, nullptr, 0,
            512, 1, 4,
            nullptr, nullptr, nullptr, 0.f);

        gemm64<<<dim3(4, 98), 256, 0, stream>>>(
            H, 2048,
            w2_t + (long long)l * 512 * 2048, 2048,
            X, 512,
            mlp_b2 + l * 512, X, 512,
            2048, 0, 0,
            nullptr, nullptr, nullptr, 0.f);
    }

    mean_k<<<64, 512, 0, stream>>>(X, (float*)d_out);
}

// Round 17
// 733.055 us; speedup vs baseline: 1.0241x; 1.0241x over previous
//
#include <hip/hip_runtime.h>
#include <hip/hip_bf16.h>

typedef __attribute__((ext_vector_type(8))) short short8;
typedef __attribute__((ext_vector_type(4))) float f32x4;

__device__ __forceinline__ unsigned short f2bf(float x) {
    unsigned int u = __builtin_bit_cast(unsigned int, x);
    unsigned int r = (u + 0x7FFFu + ((u >> 16) & 1u)) >> 16;
    return (unsigned short)r;
}

__device__ __forceinline__ void gload_lds16(const unsigned short* g, unsigned short* l) {
    __builtin_amdgcn_global_load_lds(
        (const __attribute__((address_space(1))) unsigned int*)g,
        (__attribute__((address_space(3))) unsigned int*)l, 16, 0, 0);
}

// ---------------- 128x128 / BK=64 GEMM (attnproj, MLP1, MLP2) ----------------
// Best for fat-K shapes (round 13: MLP1 83->75.6us).
// GEMM-structure search CLOSED this session (rounds 9-16):
//  - fat-acc (acc[8][4]) + default budget -> wholesale spill (WRITE 0.6-1.6GB)
//  - fat-acc + (256,1)/128KB-LDS -> no spill but 1 wave/SIMD -> latency-starved
//    (round 16: QKV 88us vs 71.5us at 3 blk/CU). Either spill or starve.
//  - 2-phase per-step overhead ~430-1700cyc rules; thin-acc + high occupancy wins.
__global__ __launch_bounds__(256) void gemm64(
    const unsigned short* __restrict__ A, int lda,
    const unsigned short* __restrict__ B, int ldb,
    void* __restrict__ Cv, int ldc,
    const float* __restrict__ bias,
    const float* __restrict__ res, int ldres,
    int K, int relu, int mode,
    unsigned short* q_out, unsigned short* k_out, unsigned short* v_out,
    float qscale)
{
    int bx = blockIdx.x, by = blockIdx.y;
    {
        const int gx = gridDim.x;
        const int total = gx * gridDim.y;
        if ((total & 7) == 0) {
            const int orig = by * gx + bx;
            const int per = total >> 3;
            const int nf = (orig & 7) * per + (orig >> 3);
            bx = nf % gx;
            by = nf / gx;
        }
    }
    const int bm = by * 128;
    const int bn = bx * 128;

    __shared__ unsigned short As[2][128][64];
    __shared__ unsigned short Bs[2][128][64];

    const int tid  = threadIdx.x;
    const int lane = tid & 63;
    const int wid  = tid >> 6;
    const int wm   = wid >> 1;
    const int wn   = wid & 1;
    const int slot = lane >> 4;
    const int lcol = lane & 15;

    const int trow = tid >> 3;               // 0..31
    const int tgrn = tid & 7;
    const int scol_dst = tgrn * 8;
    const int scol_src = (tgrn ^ (trow & 7)) * 8;

    const unsigned short* pa[4];
    const unsigned short* pb[4];
    #pragma unroll
    for (int p = 0; p < 4; ++p) {
        pa[p] = A + (long long)(bm + p * 32 + trow) * lda + scol_src;
        pb[p] = B + (long long)(bn + p * 32 + trow) * ldb + scol_src;
    }

    f32x4 acc[4][4];
    #pragma unroll
    for (int i = 0; i < 4; ++i)
        #pragma unroll
        for (int j = 0; j < 4; ++j)
            acc[i][j] = (f32x4){0.f, 0.f, 0.f, 0.f};

    const int nt = K >> 6;

    #pragma unroll
    for (int p = 0; p < 4; ++p) {
        gload_lds16(pa[p], &As[0][p * 32 + trow][scol_dst]);
        gload_lds16(pb[p], &Bs[0][p * 32 + trow][scol_dst]);
    }
    __syncthreads();

    for (int t = 0; t < nt; ++t) {
        const int cur = t & 1;
        if (t + 1 < nt) {
            const int nb = (t + 1) & 1;
            const long long koff = (long long)(t + 1) << 6;
            #pragma unroll
            for (int p = 0; p < 4; ++p) {
                gload_lds16(pa[p] + koff, &As[nb][p * 32 + trow][scol_dst]);
                gload_lds16(pb[p] + koff, &Bs[nb][p * 32 + trow][scol_dst]);
            }
        }

        short8 afr[4][2], bfr[4][2];
        #pragma unroll
        for (int mi = 0; mi < 4; ++mi) {
            const int row = wm * 64 + mi * 16 + lcol;
            #pragma unroll
            for (int ks = 0; ks < 2; ++ks) {
                const int g = ((ks * 4 + slot) ^ (lcol & 7)) * 8;
                afr[mi][ks] = *(const short8*)&As[cur][row][g];
            }
        }
        #pragma unroll
        for (int ni = 0; ni < 4; ++ni) {
            const int row = wn * 64 + ni * 16 + lcol;
            #pragma unroll
            for (int ks = 0; ks < 2; ++ks) {
                const int g = ((ks * 4 + slot) ^ (lcol & 7)) * 8;
                bfr[ni][ks] = *(const short8*)&Bs[cur][row][g];
            }
        }
        #pragma unroll
        for (int mi = 0; mi < 4; ++mi)
            #pragma unroll
            for (int ni = 0; ni < 4; ++ni)
                #pragma unroll
                for (int ks = 0; ks < 2; ++ks)
                    acc[mi][ni] = __builtin_amdgcn_mfma_f32_16x16x32_bf16(
                        afr[mi][ks], bfr[ni][ks], acc[mi][ni], 0, 0, 0);

        __syncthreads();
    }

    float* Cf = (float*)Cv;
    unsigned short* Cb = (unsigned short*)Cv;

    #pragma unroll
    for (int mi = 0; mi < 4; ++mi) {
        int rbase = bm + wm * 64 + mi * 16 + slot * 4;
        #pragma unroll
        for (int ni = 0; ni < 4; ++ni) {
            int gc = bn + wn * 64 + ni * 16 + lcol;
            float bv = bias ? bias[gc] : 0.f;
            f32x4 a = acc[mi][ni];
            #pragma unroll
            for (int rr = 0; rr < 4; ++rr) {
                int gr = rbase + rr;
                float v = a[rr] + bv;
                if (mode == 0) {
                    if (res) v += res[(long long)gr * ldres + gc];
                    if (relu) v = fmaxf(v, 0.f);
                    Cf[(long long)gr * ldc + gc] = v;
                } else { // mode 4
                    if (relu) v = fmaxf(v, 0.f);
                    Cb[(long long)gr * ldc + gc] = f2bf(v);
                }
            }
        }
    }
}

// ---------------- 128x128 BK=32 ring-3 GEMM (QKV + proj-stage) ----------------
// Best for thin-K / fat-grid shapes (3 blocks/CU: QKV 71.5us).
// mode 0: fp32 store (+res fp32, +relu)
// mode 1: proj row remap into X: orow=(r/49)*196+rowoff+r%49 (fp32)
// mode 2: qkv scatter -> q/k bf16 [z][196][128], v_t bf16 [z][128][224]
// mode 4: bf16 store (+relu)
__global__ __launch_bounds__(256) void gemm_bf16(
    const unsigned short* __restrict__ A, long long sA, int lda,
    const unsigned short* __restrict__ B, long long sB, int ldb,
    void* __restrict__ Cv, long long sC, int ldc,
    const float* __restrict__ bias,
    const float* __restrict__ res, int ldres,
    int M, int N, int K,
    int relu, int mode, int rowoff,
    unsigned short* q_out, unsigned short* k_out, unsigned short* v_out,
    float qscale)
{
    const int z = blockIdx.z;
    A += (long long)z * sA;
    B += (long long)z * sB;

    int bx = blockIdx.x, by = blockIdx.y;
    {
        const int gx = gridDim.x;
        const int total = gx * gridDim.y;
        if ((total & 7) == 0 && gridDim.z == 1) {
            const int orig = by * gx + bx;
            const int per = total >> 3;
            const int nf = (orig & 7) * per + (orig >> 3);
            bx = nf % gx;
            by = nf / gx;
        }
    }
    const int bm = by * 128;
    const int bn = bx * 128;

    __shared__ unsigned short As[3][128][32];
    __shared__ unsigned short Bs[3][128][32];

    const int tid  = threadIdx.x;
    const int lane = tid & 63;
    const int wid  = tid >> 6;
    const int wm   = wid >> 1;
    const int wn   = wid & 1;
    const int slot = lane >> 4;
    const int lcol = lane & 15;

    const int srow = tid >> 2;
    const int sgrn = tid & 3;
    const int scol_dst = sgrn * 8;
    const int scol_src = (sgrn ^ ((srow >> 1) & 3)) * 8;
    const int rslot = (slot ^ ((lcol >> 1) & 3)) * 8;

    int ga0 = bm + srow;       if (ga0 > M - 1) ga0 = M - 1;
    int ga1 = bm + 64 + srow;  if (ga1 > M - 1) ga1 = M - 1;
    int gb0 = bn + srow;       if (gb0 > N - 1) gb0 = N - 1;
    int gb1 = bn + 64 + srow;  if (gb1 > N - 1) gb1 = N - 1;
    const unsigned short* pa0 = A + (long long)ga0 * lda + scol_src;
    const unsigned short* pa1 = A + (long long)ga1 * lda + scol_src;
    const unsigned short* pb0 = B + (long long)gb0 * ldb + scol_src;
    const unsigned short* pb1 = B + (long long)gb1 * ldb + scol_src;

    f32x4 acc[4][4];
    #pragma unroll
    for (int i = 0; i < 4; ++i)
        #pragma unroll
        for (int j = 0; j < 4; ++j)
            acc[i][j] = (f32x4){0.f, 0.f, 0.f, 0.f};

    const int nt = K >> 5;

    gload_lds16(pa0, &As[0][srow][scol_dst]);
    gload_lds16(pa1, &As[0][64 + srow][scol_dst]);
    gload_lds16(pb0, &Bs[0][srow][scol_dst]);
    gload_lds16(pb1, &Bs[0][64 + srow][scol_dst]);
    if (nt > 1) {
        gload_lds16(pa0 + 32, &As[1][srow][scol_dst]);
        gload_lds16(pa1 + 32, &As[1][64 + srow][scol_dst]);
        gload_lds16(pb0 + 32, &Bs[1][srow][scol_dst]);
        gload_lds16(pb1 + 32, &Bs[1][64 + srow][scol_dst]);
    }

    int cur = 0;
    for (int t = 0; t < nt; ++t) {
        const int nxt2 = t + 2;
        if (nxt2 < nt) {
            const int nb = nxt2 % 3;
            const long long koff = (long long)nxt2 << 5;
            gload_lds16(pa0 + koff, &As[nb][srow][scol_dst]);
            gload_lds16(pa1 + koff, &As[nb][64 + srow][scol_dst]);
            gload_lds16(pb0 + koff, &Bs[nb][srow][scol_dst]);
            gload_lds16(pb1 + koff, &Bs[nb][64 + srow][scol_dst]);
        }
        if (nxt2 < nt)          asm volatile("s_waitcnt vmcnt(8)" ::: "memory");
        else if (t + 1 < nt)    asm volatile("s_waitcnt vmcnt(4)" ::: "memory");
        else                    asm volatile("s_waitcnt vmcnt(0)" ::: "memory");
        __builtin_amdgcn_s_barrier();
        __builtin_amdgcn_sched_barrier(0);

        short8 afr[4], bfr[4];
        #pragma unroll
        for (int mi = 0; mi < 4; ++mi)
            afr[mi] = *(const short8*)&As[cur][wm * 64 + mi * 16 + lcol][rslot];
        #pragma unroll
        for (int ni = 0; ni < 4; ++ni)
            bfr[ni] = *(const short8*)&Bs[cur][wn * 64 + ni * 16 + lcol][rslot];
        #pragma unroll
        for (int mi = 0; mi < 4; ++mi)
            #pragma unroll
            for (int ni = 0; ni < 4; ++ni)
                acc[mi][ni] = __builtin_amdgcn_mfma_f32_16x16x32_bf16(
                    afr[mi], bfr[ni], acc[mi][ni], 0, 0, 0);

        __builtin_amdgcn_s_barrier();
        cur = (cur == 2) ? 0 : cur + 1;
    }

    float* Cf = (float*)Cv + (mode == 0 ? (long long)z * sC : 0);
    unsigned short* Cb = (unsigned short*)Cv;

    #pragma unroll
    for (int mi = 0; mi < 4; ++mi) {
        int rbase = bm + wm * 64 + mi * 16 + slot * 4;
        #pragma unroll
        for (int ni = 0; ni < 4; ++ni) {
            int gc = bn + wn * 64 + ni * 16 + lcol;
            if (gc >= N) continue;
            float bv = bias ? bias[gc] : 0.f;
            f32x4 a = acc[mi][ni];
            #pragma unroll
            for (int rr = 0; rr < 4; ++rr) {
                int gr = rbase + rr;
                if (gr >= M) continue;
                float v = a[rr] + bv;
                if (mode == 0) {
                    if (res) v += res[(long long)gr * ldres + gc];
                    if (relu) v = fmaxf(v, 0.f);
                    Cf[(long long)gr * ldc + gc] = v;
                } else if (mode == 1) {
                    int orow = (gr / 49) * 196 + rowoff + (gr % 49);
                    Cf[(long long)orow * ldc + gc] = v;
                } else if (mode == 2) {
                    int which = gc >> 9;
                    int hh = (gc >> 7) & 3;
                    int d  = gc & 127;
                    int b_ = gr / 196, l_ = gr % 196;
                    int zz = b_ * 4 + hh;
                    if (which == 0)
                        q_out[((long long)zz * 196 + l_) * 128 + d] = f2bf(v * qscale);
                    else if (which == 1)
                        k_out[((long long)zz * 196 + l_) * 128 + d] = f2bf(v);
                    else
                        v_out[((long long)zz * 128 + d) * 224 + l_] = f2bf(v);
                } else { // mode 4
                    if (relu) v = fmaxf(v, 0.f);
                    Cb[(long long)gr * ldc + gc] = f2bf(v);
                }
            }
        }
    }
}

// ---------------- fused flash attention ----------------
__global__ __launch_bounds__(256) void flash_k(
    const unsigned short* __restrict__ q_bf,   // [256][196][128] (pre-scaled)
    const unsigned short* __restrict__ k_bf,   // [256][196][128]
    const unsigned short* __restrict__ v_t,    // [256][128][224] (V^T, d-major)
    unsigned short* __restrict__ O,            // [12544][512]
    const float* __restrict__ bt)              // [729][4] for this layer
{
    const int z = blockIdx.x;
    const int h = z & 3, bb = z >> 2;
    const int tid = threadIdx.x;
    const int w = tid >> 6;
    const int lane = tid & 63;
    const int slot = lane >> 4;
    const int lcol = lane & 15;

    __shared__ unsigned short Ps[4][16][68];

    const unsigned short* Qz = q_bf + (long long)z * 196 * 128;
    const unsigned short* Kz = k_bf + (long long)z * 196 * 128;
    const unsigned short* Vz = v_t  + (long long)z * 128 * 224;

    short8 qf[4][4];
    #pragma unroll
    for (int i = 0; i < 4; ++i) {
        const int row = (w + 4 * i) * 16 + lcol;
        #pragma unroll
        for (int ks = 0; ks < 4; ++ks)
            qf[i][ks] = *(const short8*)(Qz + (long long)row * 128 + ks * 32 + slot * 8);
    }

    f32x4 o[4][8];
    #pragma unroll
    for (int i = 0; i < 4; ++i)
        #pragma unroll
        for (int nd = 0; nd < 8; ++nd)
            o[i][nd] = (f32x4){0.f, 0.f, 0.f, 0.f};

    float m_r[4][4], l_r[4][4];
    #pragma unroll
    for (int i = 0; i < 4; ++i)
        #pragma unroll
        for (int r = 0; r < 4; ++r) { m_r[i][r] = -3e38f; l_r[i][r] = 0.f; }

    int qi1[4][4], qj1[4][4];
    #pragma unroll
    for (int i = 0; i < 4; ++i)
        #pragma unroll
        for (int r = 0; r < 4; ++r) {
            int q = (w + 4 * i) * 16 + slot * 4 + r;
            int qq = q < 195 ? q : 195;
            qi1[i][r] = qq / 14;
            qj1[i][r] = qq % 14;
        }

    #pragma unroll
    for (int kt = 0; kt < 4; ++kt) {
        const int nkj  = (kt == 3) ? 2 : 4;
        const int nksl = (kt == 3) ? 1 : 2;

        short8 kf[4][4];
        #pragma unroll
        for (int kj = 0; kj < 4; ++kj) {
            if (kj >= nkj) continue;
            const int krow = kt * 64 + kj * 16 + lcol;
            #pragma unroll
            for (int ks = 0; ks < 4; ++ks)
                kf[kj][ks] = *(const short8*)(Kz + (long long)krow * 128 + ks * 32 + slot * 8);
        }

        f32x4 s[4][4];
        __builtin_amdgcn_s_setprio(1);
        #pragma unroll
        for (int i = 0; i < 4; ++i)
            #pragma unroll
            for (int kj = 0; kj < 4; ++kj) {
                if (kj >= nkj) continue;
                f32x4 a = (f32x4){0.f, 0.f, 0.f, 0.f};
                #pragma unroll
                for (int ks = 0; ks < 4; ++ks)
                    a = __builtin_amdgcn_mfma_f32_16x16x32_bf16(qf[i][ks], kf[kj][ks], a, 0, 0, 0);
                s[i][kj] = a;
            }
        __builtin_amdgcn_s_setprio(0);

        short8 vf[8][2];
        #pragma unroll
        for (int nd = 0; nd < 8; ++nd)
            #pragma unroll
            for (int ksl = 0; ksl < 2; ++ksl) {
                if (ksl >= nksl) continue;
                vf[nd][ksl] = *(const short8*)(Vz + (long long)(nd * 16 + lcol) * 224
                                               + kt * 64 + ksl * 32 + slot * 8);
            }

        #pragma unroll
        for (int i = 0; i < 4; ++i) {
            #pragma unroll
            for (int kj = 0; kj < 4; ++kj) {
                if (kj >= nkj) continue;
                const int key = kt * 64 + kj * 16 + lcol;
                const int kk = key < 195 ? key : 195;
                const int i2 = kk / 14, j2 = kk % 14;
                #pragma unroll
                for (int r = 0; r < 4; ++r) {
                    const int idx = (qi1[i][r] - i2 + 13) * 27 + (qj1[i][r] - j2 + 13);
                    float sv = s[i][kj][r] + bt[idx * 4 + h];
                    if (key >= 196) sv = -3e38f;
                    s[i][kj][r] = sv;
                }
            }
            f32x4 pm = s[i][0];
            #pragma unroll
            for (int kj = 1; kj < 4; ++kj) {
                if (kj >= nkj) continue;
                #pragma unroll
                for (int r = 0; r < 4; ++r) pm[r] = fmaxf(pm[r], s[i][kj][r]);
            }
            #pragma unroll
            for (int r = 0; r < 4; ++r) {
                #pragma unroll
                for (int off = 1; off < 16; off <<= 1)
                    pm[r] = fmaxf(pm[r], __shfl_xor(pm[r], off));
            }
            float sf[4];
            #pragma unroll
            for (int r = 0; r < 4; ++r) {
                float mn = fmaxf(m_r[i][r], pm[r]);
                sf[r] = __expf(m_r[i][r] - mn);
                m_r[i][r] = mn;
            }
            f32x4 ladd = (f32x4){0.f, 0.f, 0.f, 0.f};
            #pragma unroll
            for (int kj = 0; kj < 4; ++kj) {
                if (kj >= nkj) continue;
                #pragma unroll
                for (int r = 0; r < 4; ++r) {
                    float p = __expf(s[i][kj][r] - m_r[i][r]);
                    s[i][kj][r] = p;
                    ladd[r] += p;
                }
            }
            #pragma unroll
            for (int r = 0; r < 4; ++r) {
                #pragma unroll
                for (int off = 1; off < 16; off <<= 1)
                    ladd[r] += __shfl_xor(ladd[r], off);
                l_r[i][r] = l_r[i][r] * sf[r] + ladd[r];
            }
            #pragma unroll
            for (int nd = 0; nd < 8; ++nd)
                #pragma unroll
                for (int r = 0; r < 4; ++r) o[i][nd][r] *= sf[r];
            #pragma unroll
            for (int kj = 0; kj < 4; ++kj) {
                if (kj >= nkj) continue;
                #pragma unroll
                for (int r = 0; r < 4; ++r)
                    Ps[w][slot * 4 + r][kj * 16 + lcol] = f2bf(s[i][kj][r]);
            }
            __builtin_amdgcn_s_setprio(1);
            #pragma unroll
            for (int ksl = 0; ksl < 2; ++ksl) {
                if (ksl >= nksl) continue;
                short8 pa = *(const short8*)&Ps[w][lcol][ksl * 32 + slot * 8];
                #pragma unroll
                for (int nd = 0; nd < 8; ++nd)
                    o[i][nd] = __builtin_amdgcn_mfma_f32_16x16x32_bf16(pa, vf[nd][ksl], o[i][nd], 0, 0, 0);
            }
            __builtin_amdgcn_s_setprio(0);
        }
    }

    #pragma unroll
    for (int i = 0; i < 4; ++i) {
        #pragma unroll
        for (int r = 0; r < 4; ++r) {
            const int q = (w + 4 * i) * 16 + slot * 4 + r;
            if (q >= 196) continue;
            const float rn = 1.f / l_r[i][r];
            unsigned short* op = O + ((long long)(bb * 196 + q)) * 512 + h * 128 + lcol;
            #pragma unroll
            for (int nd = 0; nd < 8; ++nd)
                op[nd * 16] = f2bf(o[i][nd][r] * rn);
        }
    }
}

// transpose+convert W[K][N] f32 -> Wt[N][K] bf16, layers via blockIdx.z
__global__ __launch_bounds__(256) void wconv_t(const float* __restrict__ W,
                                               unsigned short* __restrict__ Wt,
                                               int K, int N)
{
    W  += (long long)blockIdx.z * K * N;
    Wt += (long long)blockIdx.z * K * N;
    __shared__ float t[32][33];
    int tx = threadIdx.x & 31, ty = threadIdx.x >> 5;
    int n0 = blockIdx.x * 32, k0 = blockIdx.y * 32;
    #pragma unroll
    for (int j = 0; j < 4; ++j)
        t[ty + j * 8][tx] = W[(long long)(k0 + ty + j * 8) * N + n0 + tx];
    __syncthreads();
    #pragma unroll
    for (int j = 0; j < 4; ++j)
        Wt[(long long)(n0 + ty + j * 8) * K + k0 + tx] = f2bf(t[tx][ty + j * 8]);
}

__global__ __launch_bounds__(256) void wcv_k(const float* __restrict__ in,
                                             unsigned short* __restrict__ out, int n)
{
    int i = blockIdx.x * 256 + threadIdx.x;
    if (i < n) out[i] = f2bf(in[i]);
}

// adaptive avg-pool to 7x7 -> bf16 channels-last P[(b*49+t)*ch + c]
template<int F>
__global__ __launch_bounds__(256) void pool_k(const float* __restrict__ feat,
                                              unsigned short* __restrict__ P, int ch)
{
    const int S = 7 * F;
    int wv = blockIdx.x * 4 + (threadIdx.x >> 6);
    int lane = threadIdx.x & 63;
    int b = wv / ch, c = wv % ch;
    if (lane >= 49) return;
    int oh = lane / 7, ow = lane % 7;
    const float* src = feat + ((long long)b * ch + c) * (S * S) + (oh * F) * S + ow * F;
    float acc = 0.f;
    #pragma unroll
    for (int hh = 0; hh < F; ++hh) {
        const float* row = src + hh * S;
        if constexpr (F == 8) {
            float4 a = *(const float4*)row;
            float4 d = *(const float4*)(row + 4);
            acc += a.x + a.y + a.z + a.w + d.x + d.y + d.z + d.w;
        } else if constexpr (F == 4) {
            float4 a = *(const float4*)row;
            acc += a.x + a.y + a.z + a.w;
        } else if constexpr (F == 2) {
            float2 a = *(const float2*)row;
            acc += a.x + a.y;
        } else {
            acc += row[0];
        }
    }
    P[((long long)(b * 49 + lane)) * ch + c] = f2bf(acc * (1.f / (F * F)));
}

// LayerNorm over C=512 -> bf16 out; one wave per row, 4 rows/block
__global__ __launch_bounds__(256) void ln_k(const float* __restrict__ x,
                                            unsigned short* __restrict__ y,
                                            const float* __restrict__ g,
                                            const float* __restrict__ b)
{
    long long row = blockIdx.x * 4 + (threadIdx.x >> 6);
    const float* xr = x + row * 512;
    unsigned short* yr = y + row * 512;
    int lane = threadIdx.x & 63;
    float v[8];
    float s = 0.f, ss = 0.f;
    #pragma unroll
    for (int p = 0; p < 8; ++p) {
        v[p] = xr[lane + p * 64];
        s += v[p]; ss += v[p] * v[p];
    }
    #pragma unroll
    for (int off = 32; off >= 1; off >>= 1) {
        s  += __shfl_xor(s, off);
        ss += __shfl_xor(ss, off);
    }
    float mean = s * (1.f / 512.f);
    float var  = ss * (1.f / 512.f) - mean * mean;
    float rstd = rsqrtf(var + 1e-5f);
    #pragma unroll
    for (int p = 0; p < 8; ++p) {
        int c = lane + p * 64;
        yr[c] = f2bf((v[p] - mean) * rstd * g[c] + b[c]);
    }
}

__global__ __launch_bounds__(512) void mean_k(const float* __restrict__ X,
                                              float* __restrict__ out)
{
    int b = blockIdx.x, c = threadIdx.x;
    const float* xp = X + (long long)b * 196 * 512 + c;
    float s = 0.f;
    for (int t = 0; t < 196; ++t) s += xp[t * 512];
    out[b * 512 + c] = s * (1.f / 196.f);
}

extern "C" void kernel_launch(void* const* d_in, const int* in_sizes, int n_in,
                              void* d_out, int out_size, void* d_ws, size_t ws_size,
                              hipStream_t stream)
{
    const float* feat[4]   = {(const float*)d_in[0], (const float*)d_in[1],
                              (const float*)d_in[2], (const float*)d_in[3]};
    const float* proj_w[4] = {(const float*)d_in[4], (const float*)d_in[6],
                              (const float*)d_in[8], (const float*)d_in[10]};
    const float* proj_b[4] = {(const float*)d_in[5], (const float*)d_in[7],
                              (const float*)d_in[9], (const float*)d_in[11]};
    const float* ln1_g = (const float*)d_in[12];
    const float* ln1_b = (const float*)d_in[13];
    const float* qkv_w = (const float*)d_in[14];
    const float* qkv_b = (const float*)d_in[15];
    const float* bias_table = (const float*)d_in[16];
    const float* attn_pw = (const float*)d_in[17];
    const float* attn_pb = (const float*)d_in[18];
    const float* ln2_g = (const float*)d_in[19];
    const float* ln2_b = (const float*)d_in[20];
    const float* mlp_w1 = (const float*)d_in[21];
    const float* mlp_b1 = (const float*)d_in[22];
    const float* mlp_w2 = (const float*)d_in[23];
    const float* mlp_b2 = (const float*)d_in[24];

    const long long NXT = 64LL * 196 * 512;          // 6,422,528

    float* X  = (float*)d_ws;                        // [12544][512] f32
    float* S  = X + NXT;                             // scratch region
    unsigned short* O_bf = (unsigned short*)S;       // attention out [12544][512] bf16

    unsigned short* ub    = (unsigned short*)(S + 256LL * 196 * 196);
    unsigned short* XN_bf = ub;                          // [12544][512]
    unsigned short* q_bf  = XN_bf + NXT;                 // [256][196][128]
    unsigned short* k_bf  = q_bf + NXT;                  // [256][196][128]
    unsigned short* v_t   = k_bf + NXT;                  // [256][128][224]
    unsigned short* H     = q_bf;                        // MLP hidden aliases q..v_t
    unsigned short* wts   = v_t + 256LL * 128 * 224 + 256LL * 196 * 224;

    unsigned short* qkvw_t = wts;                        // 2 x [1536][512]
    unsigned short* pw_t   = qkvw_t + 2LL * 1536 * 512;  // 2 x [512][512]
    unsigned short* w1_t   = pw_t   + 2LL * 512 * 512;   // 2 x [2048][512]
    unsigned short* w2_t   = w1_t   + 2LL * 2048 * 512;  // 2 x [512][2048]
    unsigned short* pjw    = w2_t   + 2LL * 512 * 2048;
    unsigned short* P_bf   = pjw + 512LL * (96 + 192 + 384 + 768); // [3136][ch]
    unsigned short* pjw_i[4];
    const int chans[4] = {96, 192, 384, 768};
    {
        unsigned short* p = pjw;
        for (int i = 0; i < 4; ++i) { pjw_i[i] = p; p += 512LL * chans[i]; }
    }

    // ---- weight conversion ----
    wconv_t<<<dim3(1536/32, 512/32, 2), 256, 0, stream>>>(qkv_w, qkvw_t, 512, 1536);
    wconv_t<<<dim3(512/32, 512/32, 2), 256, 0, stream>>>(attn_pw, pw_t, 512, 512);
    wconv_t<<<dim3(2048/32, 512/32, 2), 256, 0, stream>>>(mlp_w1, w1_t, 512, 2048);
    wconv_t<<<dim3(512/32, 2048/32, 2), 256, 0, stream>>>(mlp_w2, w2_t, 2048, 512);
    for (int i = 0; i < 4; ++i) {
        int n = 512 * chans[i];
        wcv_k<<<(n + 255) / 256, 256, 0, stream>>>(proj_w[i], pjw_i[i], n);
    }

    // ---- pool + proj ----
    pool_k<8><<<64 * 96  / 4, 256, 0, stream>>>(feat[0], P_bf, 96);
    gemm_bf16<<<dim3(4, 25, 1), 256, 0, stream>>>(
        P_bf, 0, 96, pjw_i[0], 0, 96, X, 0, 512, proj_b[0], nullptr, 0,
        3136, 512, 96, 0, 1, 0, nullptr, nullptr, nullptr, 0.f);
    pool_k<4><<<64 * 192 / 4, 256, 0, stream>>>(feat[1], P_bf, 192);
    gemm_bf16<<<dim3(4, 25, 1), 256, 0, stream>>>(
        P_bf, 0, 192, pjw_i[1], 0, 192, X, 0, 512, proj_b[1], nullptr, 0,
        3136, 512, 192, 0, 1, 49, nullptr, nullptr, nullptr, 0.f);
    pool_k<2><<<64 * 384 / 4, 256, 0, stream>>>(feat[2], P_bf, 384);
    gemm_bf16<<<dim3(4, 25, 1), 256, 0, stream>>>(
        P_bf, 0, 384, pjw_i[2], 0, 384, X, 0, 512, proj_b[2], nullptr, 0,
        3136, 512, 384, 0, 1, 98, nullptr, nullptr, nullptr, 0.f);
    pool_k<1><<<64 * 768 / 4, 256, 0, stream>>>(feat[3], P_bf, 768);
    gemm_bf16<<<dim3(4, 25, 1), 256, 0, stream>>>(
        P_bf, 0, 768, pjw_i[3], 0, 768, X, 0, 512, proj_b[3], nullptr, 0,
        3136, 512, 768, 0, 1, 147, nullptr, nullptr, nullptr, 0.f);

    // ---- transformer layers ----
    for (int l = 0; l < 2; ++l) {
        ln_k<<<3136, 256, 0, stream>>>(X, XN_bf, ln1_g + l * 512, ln1_b + l * 512);

        // QKV: BK=32 ring-3, 3 blocks/CU (best known: 71.5us)
        gemm_bf16<<<dim3(12, 98, 1), 256, 0, stream>>>(
            XN_bf, 0, 512,
            qkvw_t + (long long)l * 1536 * 512, 0, 512,
            nullptr, 0, 0,
            qkv_b + l * 1536, nullptr, 0,
            12544, 1536, 512,
            0, 2, 0,
            q_bf, k_bf, v_t, 0.08838834764831845f);

        // fused attention
        flash_k<<<256, 256, 0, stream>>>(q_bf, k_bf, v_t, O_bf,
                                         bias_table + (long long)l * 729 * 4);

        gemm64<<<dim3(4, 98), 256, 0, stream>>>(
            O_bf, 512,
            pw_t + (long long)l * 512 * 512, 512,
            X, 512,
            attn_pb + l * 512, X, 512,
            512, 0, 0,
            nullptr, nullptr, nullptr, 0.f);

        ln_k<<<3136, 256, 0, stream>>>(X, XN_bf, ln2_g + l * 512, ln2_b + l * 512);

        gemm64<<<dim3(16, 98), 256, 0, stream>>>(
            XN_bf, 512,
            w1_t + (long long)l * 2048 * 512, 512,
            H, 2048,
            mlp_b1 + l * 2048, nullptr, 0,
            512, 1, 4,
            nullptr, nullptr, nullptr, 0.f);

        gemm64<<<dim3(4, 98), 256, 0, stream>>>(
            H, 2048,
            w2_t + (long long)l * 512 * 2048, 2048,
            X, 512,
            mlp_b2 + l * 512, X, 512,
            2048, 0, 0,
            nullptr, nullptr, nullptr, 0.f);
    }

    mean_k<<<64, 512, 0, stream>>>(X, (float*)d_out);
}

// Round 18
// 640.857 us; speedup vs baseline: 1.1714x; 1.1439x over previous
//
#include <hip/hip_runtime.h>
#include <hip/hip_bf16.h>

typedef __attribute__((ext_vector_type(8))) short short8;
typedef __attribute__((ext_vector_type(4))) float f32x4;

__device__ __forceinline__ unsigned short f2bf(float x) {
    unsigned int u = __builtin_bit_cast(unsigned int, x);
    unsigned int r = (u + 0x7FFFu + ((u >> 16) & 1u)) >> 16;
    return (unsigned short)r;
}

__device__ __forceinline__ void gload_lds16(const unsigned short* g, unsigned short* l) {
    __builtin_amdgcn_global_load_lds(
        (const __attribute__((address_space(1))) unsigned int*)g,
        (__attribute__((address_space(3))) unsigned int*)l, 16, 0, 0);
}

// ---------------- 128x128 / BK=64 GEMM (attnproj, MLP1, MLP2) ----------------
// Best for fat-K shapes (round 13: MLP1 83->75.6us).
// GEMM-structure search CLOSED (rounds 9-16): fat-acc spills under default
// budget (WRITE 0.6-1.6GB) and starves at (256,1)/1-wave-SIMD (QKV 88 vs 71.5).
// Thin-acc + high occupancy wins; 2-phase per-step overhead rules.
__global__ __launch_bounds__(256) void gemm64(
    const unsigned short* __restrict__ A, int lda,
    const unsigned short* __restrict__ B, int ldb,
    void* __restrict__ Cv, int ldc,
    const float* __restrict__ bias,
    const float* __restrict__ res, int ldres,
    int K, int relu, int mode,
    unsigned short* q_out, unsigned short* k_out, unsigned short* v_out,
    float qscale)
{
    int bx = blockIdx.x, by = blockIdx.y;
    {
        const int gx = gridDim.x;
        const int total = gx * gridDim.y;
        if ((total & 7) == 0) {
            const int orig = by * gx + bx;
            const int per = total >> 3;
            const int nf = (orig & 7) * per + (orig >> 3);
            bx = nf % gx;
            by = nf / gx;
        }
    }
    const int bm = by * 128;
    const int bn = bx * 128;

    __shared__ unsigned short As[2][128][64];
    __shared__ unsigned short Bs[2][128][64];

    const int tid  = threadIdx.x;
    const int lane = tid & 63;
    const int wid  = tid >> 6;
    const int wm   = wid >> 1;
    const int wn   = wid & 1;
    const int slot = lane >> 4;
    const int lcol = lane & 15;

    const int trow = tid >> 3;               // 0..31
    const int tgrn = tid & 7;
    const int scol_dst = tgrn * 8;
    const int scol_src = (tgrn ^ (trow & 7)) * 8;

    const unsigned short* pa[4];
    const unsigned short* pb[4];
    #pragma unroll
    for (int p = 0; p < 4; ++p) {
        pa[p] = A + (long long)(bm + p * 32 + trow) * lda + scol_src;
        pb[p] = B + (long long)(bn + p * 32 + trow) * ldb + scol_src;
    }

    f32x4 acc[4][4];
    #pragma unroll
    for (int i = 0; i < 4; ++i)
        #pragma unroll
        for (int j = 0; j < 4; ++j)
            acc[i][j] = (f32x4){0.f, 0.f, 0.f, 0.f};

    const int nt = K >> 6;

    #pragma unroll
    for (int p = 0; p < 4; ++p) {
        gload_lds16(pa[p], &As[0][p * 32 + trow][scol_dst]);
        gload_lds16(pb[p], &Bs[0][p * 32 + trow][scol_dst]);
    }
    __syncthreads();

    for (int t = 0; t < nt; ++t) {
        const int cur = t & 1;
        if (t + 1 < nt) {
            const int nb = (t + 1) & 1;
            const long long koff = (long long)(t + 1) << 6;
            #pragma unroll
            for (int p = 0; p < 4; ++p) {
                gload_lds16(pa[p] + koff, &As[nb][p * 32 + trow][scol_dst]);
                gload_lds16(pb[p] + koff, &Bs[nb][p * 32 + trow][scol_dst]);
            }
        }

        short8 afr[4][2], bfr[4][2];
        #pragma unroll
        for (int mi = 0; mi < 4; ++mi) {
            const int row = wm * 64 + mi * 16 + lcol;
            #pragma unroll
            for (int ks = 0; ks < 2; ++ks) {
                const int g = ((ks * 4 + slot) ^ (lcol & 7)) * 8;
                afr[mi][ks] = *(const short8*)&As[cur][row][g];
            }
        }
        #pragma unroll
        for (int ni = 0; ni < 4; ++ni) {
            const int row = wn * 64 + ni * 16 + lcol;
            #pragma unroll
            for (int ks = 0; ks < 2; ++ks) {
                const int g = ((ks * 4 + slot) ^ (lcol & 7)) * 8;
                bfr[ni][ks] = *(const short8*)&Bs[cur][row][g];
            }
        }
        #pragma unroll
        for (int mi = 0; mi < 4; ++mi)
            #pragma unroll
            for (int ni = 0; ni < 4; ++ni)
                #pragma unroll
                for (int ks = 0; ks < 2; ++ks)
                    acc[mi][ni] = __builtin_amdgcn_mfma_f32_16x16x32_bf16(
                        afr[mi][ks], bfr[ni][ks], acc[mi][ni], 0, 0, 0);

        __syncthreads();
    }

    float* Cf = (float*)Cv;
    unsigned short* Cb = (unsigned short*)Cv;

    #pragma unroll
    for (int mi = 0; mi < 4; ++mi) {
        int rbase = bm + wm * 64 + mi * 16 + slot * 4;
        #pragma unroll
        for (int ni = 0; ni < 4; ++ni) {
            int gc = bn + wn * 64 + ni * 16 + lcol;
            float bv = bias ? bias[gc] : 0.f;
            f32x4 a = acc[mi][ni];
            #pragma unroll
            for (int rr = 0; rr < 4; ++rr) {
                int gr = rbase + rr;
                float v = a[rr] + bv;
                if (mode == 0) {
                    if (res) v += res[(long long)gr * ldres + gc];
                    if (relu) v = fmaxf(v, 0.f);
                    Cf[(long long)gr * ldc + gc] = v;
                } else { // mode 4
                    if (relu) v = fmaxf(v, 0.f);
                    Cb[(long long)gr * ldc + gc] = f2bf(v);
                }
            }
        }
    }
}

// ---------------- 128x128 BK=32 ring-3 GEMM (QKV) ----------------
// Best for thin-K / fat-grid shapes (3 blocks/CU: QKV 71.5us).
// mode 2: qkv scatter -> q/k bf16 [z][196][128], v_t bf16 [z][128][224]
__global__ __launch_bounds__(256) void gemm_bf16(
    const unsigned short* __restrict__ A, int lda,
    const unsigned short* __restrict__ B, int ldb,
    const float* __restrict__ bias,
    int M, int N, int K,
    unsigned short* q_out, unsigned short* k_out, unsigned short* v_out,
    float qscale)
{
    int bx = blockIdx.x, by = blockIdx.y;
    {
        const int gx = gridDim.x;
        const int total = gx * gridDim.y;
        if ((total & 7) == 0) {
            const int orig = by * gx + bx;
            const int per = total >> 3;
            const int nf = (orig & 7) * per + (orig >> 3);
            bx = nf % gx;
            by = nf / gx;
        }
    }
    const int bm = by * 128;
    const int bn = bx * 128;

    __shared__ unsigned short As[3][128][32];
    __shared__ unsigned short Bs[3][128][32];

    const int tid  = threadIdx.x;
    const int lane = tid & 63;
    const int wid  = tid >> 6;
    const int wm   = wid >> 1;
    const int wn   = wid & 1;
    const int slot = lane >> 4;
    const int lcol = lane & 15;

    const int srow = tid >> 2;
    const int sgrn = tid & 3;
    const int scol_dst = sgrn * 8;
    const int scol_src = (sgrn ^ ((srow >> 1) & 3)) * 8;
    const int rslot = (slot ^ ((lcol >> 1) & 3)) * 8;

    const unsigned short* pa0 = A + (long long)(bm + srow) * lda + scol_src;
    const unsigned short* pa1 = A + (long long)(bm + 64 + srow) * lda + scol_src;
    const unsigned short* pb0 = B + (long long)(bn + srow) * ldb + scol_src;
    const unsigned short* pb1 = B + (long long)(bn + 64 + srow) * ldb + scol_src;

    f32x4 acc[4][4];
    #pragma unroll
    for (int i = 0; i < 4; ++i)
        #pragma unroll
        for (int j = 0; j < 4; ++j)
            acc[i][j] = (f32x4){0.f, 0.f, 0.f, 0.f};

    const int nt = K >> 5;

    gload_lds16(pa0, &As[0][srow][scol_dst]);
    gload_lds16(pa1, &As[0][64 + srow][scol_dst]);
    gload_lds16(pb0, &Bs[0][srow][scol_dst]);
    gload_lds16(pb1, &Bs[0][64 + srow][scol_dst]);
    if (nt > 1) {
        gload_lds16(pa0 + 32, &As[1][srow][scol_dst]);
        gload_lds16(pa1 + 32, &As[1][64 + srow][scol_dst]);
        gload_lds16(pb0 + 32, &Bs[1][srow][scol_dst]);
        gload_lds16(pb1 + 32, &Bs[1][64 + srow][scol_dst]);
    }

    int cur = 0;
    for (int t = 0; t < nt; ++t) {
        const int nxt2 = t + 2;
        if (nxt2 < nt) {
            const int nb = nxt2 % 3;
            const long long koff = (long long)nxt2 << 5;
            gload_lds16(pa0 + koff, &As[nb][srow][scol_dst]);
            gload_lds16(pa1 + koff, &As[nb][64 + srow][scol_dst]);
            gload_lds16(pb0 + koff, &Bs[nb][srow][scol_dst]);
            gload_lds16(pb1 + koff, &Bs[nb][64 + srow][scol_dst]);
        }
        if (nxt2 < nt)          asm volatile("s_waitcnt vmcnt(8)" ::: "memory");
        else if (t + 1 < nt)    asm volatile("s_waitcnt vmcnt(4)" ::: "memory");
        else                    asm volatile("s_waitcnt vmcnt(0)" ::: "memory");
        __builtin_amdgcn_s_barrier();
        __builtin_amdgcn_sched_barrier(0);

        short8 afr[4], bfr[4];
        #pragma unroll
        for (int mi = 0; mi < 4; ++mi)
            afr[mi] = *(const short8*)&As[cur][wm * 64 + mi * 16 + lcol][rslot];
        #pragma unroll
        for (int ni = 0; ni < 4; ++ni)
            bfr[ni] = *(const short8*)&Bs[cur][wn * 64 + ni * 16 + lcol][rslot];
        #pragma unroll
        for (int mi = 0; mi < 4; ++mi)
            #pragma unroll
            for (int ni = 0; ni < 4; ++ni)
                acc[mi][ni] = __builtin_amdgcn_mfma_f32_16x16x32_bf16(
                    afr[mi], bfr[ni], acc[mi][ni], 0, 0, 0);

        __builtin_amdgcn_s_barrier();
        cur = (cur == 2) ? 0 : cur + 1;
    }

    #pragma unroll
    for (int mi = 0; mi < 4; ++mi) {
        int rbase = bm + wm * 64 + mi * 16 + slot * 4;
        #pragma unroll
        for (int ni = 0; ni < 4; ++ni) {
            int gc = bn + wn * 64 + ni * 16 + lcol;
            float bv = bias[gc];
            f32x4 a = acc[mi][ni];
            int which = gc >> 9;
            int hh = (gc >> 7) & 3;
            int d  = gc & 127;
            #pragma unroll
            for (int rr = 0; rr < 4; ++rr) {
                int gr = rbase + rr;
                float v = a[rr] + bv;
                int b_ = gr / 196, l_ = gr % 196;
                int zz = b_ * 4 + hh;
                if (which == 0)
                    q_out[((long long)zz * 196 + l_) * 128 + d] = f2bf(v * qscale);
                else if (which == 1)
                    k_out[((long long)zz * 196 + l_) * 128 + d] = f2bf(v);
                else
                    v_out[((long long)zz * 128 + d) * 224 + l_] = f2bf(v);
            }
        }
    }
}

// ---------------- batched proj GEMM (all 4 scales, one launch) ----------------
// z = scale; K = 96<<z; rowoff = 49*z. BK=32 ring-3 structure, mode-1 remap.
struct ProjArgs {
    const unsigned short* P0; const unsigned short* P1;
    const unsigned short* P2; const unsigned short* P3;
    const unsigned short* W0; const unsigned short* W1;
    const unsigned short* W2; const unsigned short* W3;
    const float* b0; const float* b1; const float* b2; const float* b3;
};

__global__ __launch_bounds__(256) void gemm_proj(ProjArgs args, float* __restrict__ C)
{
    const int zi = blockIdx.z;
    const unsigned short* A; const unsigned short* B; const float* bias;
    int K;
    if (zi == 0)      { A = args.P0; B = args.W0; bias = args.b0; K = 96;  }
    else if (zi == 1) { A = args.P1; B = args.W1; bias = args.b1; K = 192; }
    else if (zi == 2) { A = args.P2; B = args.W2; bias = args.b2; K = 384; }
    else              { A = args.P3; B = args.W3; bias = args.b3; K = 768; }
    const int rowoff = 49 * zi;
    const int M = 3136, N = 512;
    const int lda = K, ldb = K;

    const int bm = blockIdx.y * 128;
    const int bn = blockIdx.x * 128;

    __shared__ unsigned short As[3][128][32];
    __shared__ unsigned short Bs[3][128][32];

    const int tid  = threadIdx.x;
    const int lane = tid & 63;
    const int wid  = tid >> 6;
    const int wm   = wid >> 1;
    const int wn   = wid & 1;
    const int slot = lane >> 4;
    const int lcol = lane & 15;

    const int srow = tid >> 2;
    const int sgrn = tid & 3;
    const int scol_dst = sgrn * 8;
    const int scol_src = (sgrn ^ ((srow >> 1) & 3)) * 8;
    const int rslot = (slot ^ ((lcol >> 1) & 3)) * 8;

    int ga0 = bm + srow;       if (ga0 > M - 1) ga0 = M - 1;
    int ga1 = bm + 64 + srow;  if (ga1 > M - 1) ga1 = M - 1;
    const unsigned short* pa0 = A + (long long)ga0 * lda + scol_src;
    const unsigned short* pa1 = A + (long long)ga1 * lda + scol_src;
    const unsigned short* pb0 = B + (long long)(bn + srow) * ldb + scol_src;
    const unsigned short* pb1 = B + (long long)(bn + 64 + srow) * ldb + scol_src;

    f32x4 acc[4][4];
    #pragma unroll
    for (int i = 0; i < 4; ++i)
        #pragma unroll
        for (int j = 0; j < 4; ++j)
            acc[i][j] = (f32x4){0.f, 0.f, 0.f, 0.f};

    const int nt = K >> 5;   // 3,6,12,24

    gload_lds16(pa0, &As[0][srow][scol_dst]);
    gload_lds16(pa1, &As[0][64 + srow][scol_dst]);
    gload_lds16(pb0, &Bs[0][srow][scol_dst]);
    gload_lds16(pb1, &Bs[0][64 + srow][scol_dst]);
    gload_lds16(pa0 + 32, &As[1][srow][scol_dst]);
    gload_lds16(pa1 + 32, &As[1][64 + srow][scol_dst]);
    gload_lds16(pb0 + 32, &Bs[1][srow][scol_dst]);
    gload_lds16(pb1 + 32, &Bs[1][64 + srow][scol_dst]);

    int cur = 0;
    for (int t = 0; t < nt; ++t) {
        const int nxt2 = t + 2;
        if (nxt2 < nt) {
            const int nb = nxt2 % 3;
            const long long koff = (long long)nxt2 << 5;
            gload_lds16(pa0 + koff, &As[nb][srow][scol_dst]);
            gload_lds16(pa1 + koff, &As[nb][64 + srow][scol_dst]);
            gload_lds16(pb0 + koff, &Bs[nb][srow][scol_dst]);
            gload_lds16(pb1 + koff, &Bs[nb][64 + srow][scol_dst]);
        }
        if (nxt2 < nt)          asm volatile("s_waitcnt vmcnt(8)" ::: "memory");
        else if (t + 1 < nt)    asm volatile("s_waitcnt vmcnt(4)" ::: "memory");
        else                    asm volatile("s_waitcnt vmcnt(0)" ::: "memory");
        __builtin_amdgcn_s_barrier();
        __builtin_amdgcn_sched_barrier(0);

        short8 afr[4], bfr[4];
        #pragma unroll
        for (int mi = 0; mi < 4; ++mi)
            afr[mi] = *(const short8*)&As[cur][wm * 64 + mi * 16 + lcol][rslot];
        #pragma unroll
        for (int ni = 0; ni < 4; ++ni)
            bfr[ni] = *(const short8*)&Bs[cur][wn * 64 + ni * 16 + lcol][rslot];
        #pragma unroll
        for (int mi = 0; mi < 4; ++mi)
            #pragma unroll
            for (int ni = 0; ni < 4; ++ni)
                acc[mi][ni] = __builtin_amdgcn_mfma_f32_16x16x32_bf16(
                    afr[mi], bfr[ni], acc[mi][ni], 0, 0, 0);

        __builtin_amdgcn_s_barrier();
        cur = (cur == 2) ? 0 : cur + 1;
    }

    #pragma unroll
    for (int mi = 0; mi < 4; ++mi) {
        int rbase = bm + wm * 64 + mi * 16 + slot * 4;
        #pragma unroll
        for (int ni = 0; ni < 4; ++ni) {
            int gc = bn + wn * 64 + ni * 16 + lcol;
            float bv = bias[gc];
            f32x4 a = acc[mi][ni];
            #pragma unroll
            for (int rr = 0; rr < 4; ++rr) {
                int gr = rbase + rr;
                if (gr >= M) continue;
                float v = a[rr] + bv;
                int orow = (gr / 49) * 196 + rowoff + (gr % 49);
                C[(long long)orow * 512 + gc] = v;
            }
        }
    }
}

// ---------------- fused flash attention ----------------
__global__ __launch_bounds__(256) void flash_k(
    const unsigned short* __restrict__ q_bf,
    const unsigned short* __restrict__ k_bf,
    const unsigned short* __restrict__ v_t,
    unsigned short* __restrict__ O,
    const float* __restrict__ bt)
{
    const int z = blockIdx.x;
    const int h = z & 3, bb = z >> 2;
    const int tid = threadIdx.x;
    const int w = tid >> 6;
    const int lane = tid & 63;
    const int slot = lane >> 4;
    const int lcol = lane & 15;

    __shared__ unsigned short Ps[4][16][68];

    const unsigned short* Qz = q_bf + (long long)z * 196 * 128;
    const unsigned short* Kz = k_bf + (long long)z * 196 * 128;
    const unsigned short* Vz = v_t  + (long long)z * 128 * 224;

    short8 qf[4][4];
    #pragma unroll
    for (int i = 0; i < 4; ++i) {
        const int row = (w + 4 * i) * 16 + lcol;
        #pragma unroll
        for (int ks = 0; ks < 4; ++ks)
            qf[i][ks] = *(const short8*)(Qz + (long long)row * 128 + ks * 32 + slot * 8);
    }

    f32x4 o[4][8];
    #pragma unroll
    for (int i = 0; i < 4; ++i)
        #pragma unroll
        for (int nd = 0; nd < 8; ++nd)
            o[i][nd] = (f32x4){0.f, 0.f, 0.f, 0.f};

    float m_r[4][4], l_r[4][4];
    #pragma unroll
    for (int i = 0; i < 4; ++i)
        #pragma unroll
        for (int r = 0; r < 4; ++r) { m_r[i][r] = -3e38f; l_r[i][r] = 0.f; }

    int qi1[4][4], qj1[4][4];
    #pragma unroll
    for (int i = 0; i < 4; ++i)
        #pragma unroll
        for (int r = 0; r < 4; ++r) {
            int q = (w + 4 * i) * 16 + slot * 4 + r;
            int qq = q < 195 ? q : 195;
            qi1[i][r] = qq / 14;
            qj1[i][r] = qq % 14;
        }

    #pragma unroll
    for (int kt = 0; kt < 4; ++kt) {
        const int nkj  = (kt == 3) ? 2 : 4;
        const int nksl = (kt == 3) ? 1 : 2;

        short8 kf[4][4];
        #pragma unroll
        for (int kj = 0; kj < 4; ++kj) {
            if (kj >= nkj) continue;
            const int krow = kt * 64 + kj * 16 + lcol;
            #pragma unroll
            for (int ks = 0; ks < 4; ++ks)
                kf[kj][ks] = *(const short8*)(Kz + (long long)krow * 128 + ks * 32 + slot * 8);
        }

        f32x4 s[4][4];
        __builtin_amdgcn_s_setprio(1);
        #pragma unroll
        for (int i = 0; i < 4; ++i)
            #pragma unroll
            for (int kj = 0; kj < 4; ++kj) {
                if (kj >= nkj) continue;
                f32x4 a = (f32x4){0.f, 0.f, 0.f, 0.f};
                #pragma unroll
                for (int ks = 0; ks < 4; ++ks)
                    a = __builtin_amdgcn_mfma_f32_16x16x32_bf16(qf[i][ks], kf[kj][ks], a, 0, 0, 0);
                s[i][kj] = a;
            }
        __builtin_amdgcn_s_setprio(0);

        short8 vf[8][2];
        #pragma unroll
        for (int nd = 0; nd < 8; ++nd)
            #pragma unroll
            for (int ksl = 0; ksl < 2; ++ksl) {
                if (ksl >= nksl) continue;
                vf[nd][ksl] = *(const short8*)(Vz + (long long)(nd * 16 + lcol) * 224
                                               + kt * 64 + ksl * 32 + slot * 8);
            }

        #pragma unroll
        for (int i = 0; i < 4; ++i) {
            #pragma unroll
            for (int kj = 0; kj < 4; ++kj) {
                if (kj >= nkj) continue;
                const int key = kt * 64 + kj * 16 + lcol;
                const int kk = key < 195 ? key : 195;
                const int i2 = kk / 14, j2 = kk % 14;
                #pragma unroll
                for (int r = 0; r < 4; ++r) {
                    const int idx = (qi1[i][r] - i2 + 13) * 27 + (qj1[i][r] - j2 + 13);
                    float sv = s[i][kj][r] + bt[idx * 4 + h];
                    if (key >= 196) sv = -3e38f;
                    s[i][kj][r] = sv;
                }
            }
            f32x4 pm = s[i][0];
            #pragma unroll
            for (int kj = 1; kj < 4; ++kj) {
                if (kj >= nkj) continue;
                #pragma unroll
                for (int r = 0; r < 4; ++r) pm[r] = fmaxf(pm[r], s[i][kj][r]);
            }
            #pragma unroll
            for (int r = 0; r < 4; ++r) {
                #pragma unroll
                for (int off = 1; off < 16; off <<= 1)
                    pm[r] = fmaxf(pm[r], __shfl_xor(pm[r], off));
            }
            float sf[4];
            #pragma unroll
            for (int r = 0; r < 4; ++r) {
                float mn = fmaxf(m_r[i][r], pm[r]);
                sf[r] = __expf(m_r[i][r] - mn);
                m_r[i][r] = mn;
            }
            f32x4 ladd = (f32x4){0.f, 0.f, 0.f, 0.f};
            #pragma unroll
            for (int kj = 0; kj < 4; ++kj) {
                if (kj >= nkj) continue;
                #pragma unroll
                for (int r = 0; r < 4; ++r) {
                    float p = __expf(s[i][kj][r] - m_r[i][r]);
                    s[i][kj][r] = p;
                    ladd[r] += p;
                }
            }
            #pragma unroll
            for (int r = 0; r < 4; ++r) {
                #pragma unroll
                for (int off = 1; off < 16; off <<= 1)
                    ladd[r] += __shfl_xor(ladd[r], off);
                l_r[i][r] = l_r[i][r] * sf[r] + ladd[r];
            }
            #pragma unroll
            for (int nd = 0; nd < 8; ++nd)
                #pragma unroll
                for (int r = 0; r < 4; ++r) o[i][nd][r] *= sf[r];
            #pragma unroll
            for (int kj = 0; kj < 4; ++kj) {
                if (kj >= nkj) continue;
                #pragma unroll
                for (int r = 0; r < 4; ++r)
                    Ps[w][slot * 4 + r][kj * 16 + lcol] = f2bf(s[i][kj][r]);
            }
            __builtin_amdgcn_s_setprio(1);
            #pragma unroll
            for (int ksl = 0; ksl < 2; ++ksl) {
                if (ksl >= nksl) continue;
                short8 pa = *(const short8*)&Ps[w][lcol][ksl * 32 + slot * 8];
                #pragma unroll
                for (int nd = 0; nd < 8; ++nd)
                    o[i][nd] = __builtin_amdgcn_mfma_f32_16x16x32_bf16(pa, vf[nd][ksl], o[i][nd], 0, 0, 0);
            }
            __builtin_amdgcn_s_setprio(0);
        }
    }

    #pragma unroll
    for (int i = 0; i < 4; ++i) {
        #pragma unroll
        for (int r = 0; r < 4; ++r) {
            const int q = (w + 4 * i) * 16 + slot * 4 + r;
            if (q >= 196) continue;
            const float rn = 1.f / l_r[i][r];
            unsigned short* op = O + ((long long)(bb * 196 + q)) * 512 + h * 128 + lcol;
            #pragma unroll
            for (int nd = 0; nd < 8; ++nd)
                op[nd * 16] = f2bf(o[i][nd][r] * rn);
        }
    }
}

// transpose+convert W[K][N] f32 -> Wt[N][K] bf16, layers via blockIdx.z
__global__ __launch_bounds__(256) void wconv_t(const float* __restrict__ W,
                                               unsigned short* __restrict__ Wt,
                                               int K, int N)
{
    W  += (long long)blockIdx.z * K * N;
    Wt += (long long)blockIdx.z * K * N;
    __shared__ float t[32][33];
    int tx = threadIdx.x & 31, ty = threadIdx.x >> 5;
    int n0 = blockIdx.x * 32, k0 = blockIdx.y * 32;
    #pragma unroll
    for (int j = 0; j < 4; ++j)
        t[ty + j * 8][tx] = W[(long long)(k0 + ty + j * 8) * N + n0 + tx];
    __syncthreads();
    #pragma unroll
    for (int j = 0; j < 4; ++j)
        Wt[(long long)(n0 + ty + j * 8) * K + k0 + tx] = f2bf(t[tx][ty + j * 8]);
}

__global__ __launch_bounds__(256) void wcv_k(const float* __restrict__ in,
                                             unsigned short* __restrict__ out, int n)
{
    int i = blockIdx.x * 256 + threadIdx.x;
    if (i < n) out[i] = f2bf(in[i]);
}

// adaptive avg-pool to 7x7 -> bf16 channels-last P[(b*49+t)*ch + c]
template<int F>
__global__ __launch_bounds__(256) void pool_k(const float* __restrict__ feat,
                                              unsigned short* __restrict__ P, int ch)
{
    const int S = 7 * F;
    int wv = blockIdx.x * 4 + (threadIdx.x >> 6);
    int lane = threadIdx.x & 63;
    int b = wv / ch, c = wv % ch;
    if (lane >= 49) return;
    int oh = lane / 7, ow = lane % 7;
    const float* src = feat + ((long long)b * ch + c) * (S * S) + (oh * F) * S + ow * F;
    float acc = 0.f;
    #pragma unroll
    for (int hh = 0; hh < F; ++hh) {
        const float* row = src + hh * S;
        if constexpr (F == 8) {
            float4 a = *(const float4*)row;
            float4 d = *(const float4*)(row + 4);
            acc += a.x + a.y + a.z + a.w + d.x + d.y + d.z + d.w;
        } else if constexpr (F == 4) {
            float4 a = *(const float4*)row;
            acc += a.x + a.y + a.z + a.w;
        } else if constexpr (F == 2) {
            float2 a = *(const float2*)row;
            acc += a.x + a.y;
        } else {
            acc += row[0];
        }
    }
    P[((long long)(b * 49 + lane)) * ch + c] = f2bf(acc * (1.f / (F * F)));
}

// LayerNorm over C=512 -> bf16 out; one wave per row, 4 rows/block
__global__ __launch_bounds__(256) void ln_k(const float* __restrict__ x,
                                            unsigned short* __restrict__ y,
                                            const float* __restrict__ g,
                                            const float* __restrict__ b)
{
    long long row = blockIdx.x * 4 + (threadIdx.x >> 6);
    const float* xr = x + row * 512;
    unsigned short* yr = y + row * 512;
    int lane = threadIdx.x & 63;
    float v[8];
    float s = 0.f, ss = 0.f;
    #pragma unroll
    for (int p = 0; p < 8; ++p) {
        v[p] = xr[lane + p * 64];
        s += v[p]; ss += v[p] * v[p];
    }
    #pragma unroll
    for (int off = 32; off >= 1; off >>= 1) {
        s  += __shfl_xor(s, off);
        ss += __shfl_xor(ss, off);
    }
    float mean = s * (1.f / 512.f);
    float var  = ss * (1.f / 512.f) - mean * mean;
    float rstd = rsqrtf(var + 1e-5f);
    #pragma unroll
    for (int p = 0; p < 8; ++p) {
        int c = lane + p * 64;
        yr[c] = f2bf((v[p] - mean) * rstd * g[c] + b[c]);
    }
}

__global__ __launch_bounds__(512) void mean_k(const float* __restrict__ X,
                                              float* __restrict__ out)
{
    int b = blockIdx.x, c = threadIdx.x;
    const float* xp = X + (long long)b * 196 * 512 + c;
    float s = 0.f;
    for (int t = 0; t < 196; ++t) s += xp[t * 512];
    out[b * 512 + c] = s * (1.f / 196.f);
}

extern "C" void kernel_launch(void* const* d_in, const int* in_sizes, int n_in,
                              void* d_out, int out_size, void* d_ws, size_t ws_size,
                              hipStream_t stream)
{
    const float* feat[4]   = {(const float*)d_in[0], (const float*)d_in[1],
                              (const float*)d_in[2], (const float*)d_in[3]};
    const float* proj_w[4] = {(const float*)d_in[4], (const float*)d_in[6],
                              (const float*)d_in[8], (const float*)d_in[10]};
    const float* proj_b[4] = {(const float*)d_in[5], (const float*)d_in[7],
                              (const float*)d_in[9], (const float*)d_in[11]};
    const float* ln1_g = (const float*)d_in[12];
    const float* ln1_b = (const float*)d_in[13];
    const float* qkv_w = (const float*)d_in[14];
    const float* qkv_b = (const float*)d_in[15];
    const float* bias_table = (const float*)d_in[16];
    const float* attn_pw = (const float*)d_in[17];
    const float* attn_pb = (const float*)d_in[18];
    const float* ln2_g = (const float*)d_in[19];
    const float* ln2_b = (const float*)d_in[20];
    const float* mlp_w1 = (const float*)d_in[21];
    const float* mlp_b1 = (const float*)d_in[22];
    const float* mlp_w2 = (const float*)d_in[23];
    const float* mlp_b2 = (const float*)d_in[24];

    const long long NXT = 64LL * 196 * 512;          // 6,422,528

    float* X  = (float*)d_ws;                        // [12544][512] f32
    float* S  = X + NXT;                             // scratch region (39.3MB)
    unsigned short* O_bf = (unsigned short*)S;       // attention out [12544][512] bf16

    // per-scale pooled-feature buffers live in S region past O_bf (dead space)
    unsigned short* Sreg = (unsigned short*)S;
    unsigned short* Pb[4];
    {
        unsigned short* p = Sreg + 7000000LL;        // past O_bf (6,422,528 shorts)
        const int chs[4] = {96, 192, 384, 768};
        for (int i = 0; i < 4; ++i) { Pb[i] = p; p += 3136LL * chs[i]; }
    }

    unsigned short* ub    = (unsigned short*)(S + 256LL * 196 * 196);
    unsigned short* XN_bf = ub;                          // [12544][512]
    unsigned short* q_bf  = XN_bf + NXT;                 // [256][196][128]
    unsigned short* k_bf  = q_bf + NXT;                  // [256][196][128]
    unsigned short* v_t   = k_bf + NXT;                  // [256][128][224]
    unsigned short* H     = q_bf;                        // MLP hidden aliases q..v_t
    unsigned short* wts   = v_t + 256LL * 128 * 224 + 256LL * 196 * 224;

    unsigned short* qkvw_t = wts;                        // 2 x [1536][512]
    unsigned short* pw_t   = qkvw_t + 2LL * 1536 * 512;  // 2 x [512][512]
    unsigned short* w1_t   = pw_t   + 2LL * 512 * 512;   // 2 x [2048][512]
    unsigned short* w2_t   = w1_t   + 2LL * 2048 * 512;  // 2 x [512][2048]
    unsigned short* pjw    = w2_t   + 2LL * 512 * 2048;
    unsigned short* pjw_i[4];
    const int chans[4] = {96, 192, 384, 768};
    {
        unsigned short* p = pjw;
        for (int i = 0; i < 4; ++i) { pjw_i[i] = p; p += 512LL * chans[i]; }
    }

    // ---- weight conversion ----
    wconv_t<<<dim3(1536/32, 512/32, 2), 256, 0, stream>>>(qkv_w, qkvw_t, 512, 1536);
    wconv_t<<<dim3(512/32, 512/32, 2), 256, 0, stream>>>(attn_pw, pw_t, 512, 512);
    wconv_t<<<dim3(2048/32, 512/32, 2), 256, 0, stream>>>(mlp_w1, w1_t, 512, 2048);
    wconv_t<<<dim3(512/32, 2048/32, 2), 256, 0, stream>>>(mlp_w2, w2_t, 2048, 512);
    for (int i = 0; i < 4; ++i) {
        int n = 512 * chans[i];
        wcv_k<<<(n + 255) / 256, 256, 0, stream>>>(proj_w[i], pjw_i[i], n);
    }

    // ---- pools (separate buffers), then one batched proj GEMM ----
    pool_k<8><<<64 * 96  / 4, 256, 0, stream>>>(feat[0], Pb[0], 96);
    pool_k<4><<<64 * 192 / 4, 256, 0, stream>>>(feat[1], Pb[1], 192);
    pool_k<2><<<64 * 384 / 4, 256, 0, stream>>>(feat[2], Pb[2], 384);
    pool_k<1><<<64 * 768 / 4, 256, 0, stream>>>(feat[3], Pb[3], 768);
    {
        ProjArgs pa;
        pa.P0 = Pb[0]; pa.P1 = Pb[1]; pa.P2 = Pb[2]; pa.P3 = Pb[3];
        pa.W0 = pjw_i[0]; pa.W1 = pjw_i[1]; pa.W2 = pjw_i[2]; pa.W3 = pjw_i[3];
        pa.b0 = proj_b[0]; pa.b1 = proj_b[1]; pa.b2 = proj_b[2]; pa.b3 = proj_b[3];
        gemm_proj<<<dim3(4, 25, 4), 256, 0, stream>>>(pa, X);
    }

    // ---- transformer layers ----
    for (int l = 0; l < 2; ++l) {
        ln_k<<<3136, 256, 0, stream>>>(X, XN_bf, ln1_g + l * 512, ln1_b + l * 512);

        // QKV: BK=32 ring-3, 3 blocks/CU (best known: 71.5us)
        gemm_bf16<<<dim3(12, 98), 256, 0, stream>>>(
            XN_bf, 512,
            qkvw_t + (long long)l * 1536 * 512, 512,
            qkv_b + l * 1536,
            12544, 1536, 512,
            q_bf, k_bf, v_t, 0.08838834764831845f);

        // fused attention
        flash_k<<<256, 256, 0, stream>>>(q_bf, k_bf, v_t, O_bf,
                                         bias_table + (long long)l * 729 * 4);

        gemm64<<<dim3(4, 98), 256, 0, stream>>>(
            O_bf, 512,
            pw_t + (long long)l * 512 * 512, 512,
            X, 512,
            attn_pb + l * 512, X, 512,
            512, 0, 0,
            nullptr, nullptr, nullptr, 0.f);

        ln_k<<<3136, 256, 0, stream>>>(X, XN_bf, ln2_g + l * 512, ln2_b + l * 512);

        gemm64<<<dim3(16, 98), 256, 0, stream>>>(
            XN_bf, 512,
            w1_t + (long long)l * 2048 * 512, 512,
            H, 2048,
            mlp_b1 + l * 2048, nullptr, 0,
            512, 1, 4,
            nullptr, nullptr, nullptr, 0.f);

        gemm64<<<dim3(4, 98), 256, 0, stream>>>(
            H, 2048,
            w2_t + (long long)l * 512 * 2048, 2048,
            X, 512,
            mlp_b2 + l * 512, X, 512,
            2048, 0, 0,
            nullptr, nullptr, nullptr, 0.f);
    }

    mean_k<<<64, 512, 0, stream>>>(X, (float*)d_out);
}